// Round 3
// baseline (330.675 us; speedup 1.0000x reference)
//
#include <hip/hip_runtime.h>

typedef __attribute__((ext_vector_type(8))) short short8;
typedef __attribute__((ext_vector_type(4))) float floatx4;

#define INVC 0.9995003746877732f
#define MSPLIT 16

__device__ __forceinline__ unsigned short f2bf(float f) {
    union { float f; unsigned int u; } c; c.f = f;
    unsigned int r = c.u + 0x7fffu + ((c.u >> 16) & 1u);
    return (unsigned short)(r >> 16);
}
__device__ __forceinline__ float bf2f(unsigned short u) {
    union { unsigned int u; float f; } c; c.u = ((unsigned int)u) << 16;
    return c.f;
}
// async global->LDS, 16B per lane; lds dest = wave-uniform base + lane*16
__device__ __forceinline__ void gld_lds16(const unsigned short* g, unsigned short* l) {
    __builtin_amdgcn_global_load_lds(
        (const __attribute__((address_space(1))) unsigned int*)g,
        (__attribute__((address_space(3))) unsigned int*)l, 16, 0, 0);
}

// ---------------------------------------------------------------------------
// Prep: fp32->bf16 casts of activations + transpose-cast of 8 weight matrices
// ---------------------------------------------------------------------------
struct PrepPtrs {
    const float* src_pix; const float* src_mem;
    unsigned short* dst_pix; unsigned short* dst_mem;
    const float* W[8]; unsigned short* Wt[8];
};

__global__ __launch_bounds__(256) void prep_kernel(PrepPtrs P) {
    __shared__ float T[32][33];
    const int bid = blockIdx.x, t = threadIdx.x;
    if (bid < 4224) {
        const float* src; unsigned short* dst; int base;
        if (bid < 4096) { src = P.src_pix; dst = P.dst_pix; base = bid * 1024; }
        else            { src = P.src_mem; dst = P.dst_mem; base = (bid - 4096) * 1024; }
        int i = base + t * 4;
        float4 v = *(const float4*)(src + i);
        unsigned long long pk = (unsigned long long)f2bf(v.x)
            | ((unsigned long long)f2bf(v.y) << 16)
            | ((unsigned long long)f2bf(v.z) << 32)
            | ((unsigned long long)f2bf(v.w) << 48);
        *(unsigned long long*)(dst + i) = pk;
        return;
    }
    int rel = bid - 4224;
    const int KD[8]  = {128,128,256,256,256,256,128,2048};
    const int ND[8]  = {256,256,512,512,128,128,2048,128};
    const int CNT[8] = {32,32,128,128,32,32,256,256};
    int wi = 0;
    #pragma unroll
    for (int k = 0; k < 8; ++k) { if (rel >= CNT[k] && wi == k) { rel -= CNT[k]; wi = k + 1; } }
    const int K = KD[wi], N = ND[wi];
    const int ntn = N >> 5;
    const int tn = rel % ntn, tk = rel / ntn;
    const int n0 = tn * 32, k0 = tk * 32;
    const float* W = P.W[wi];
    unsigned short* Wt = P.Wt[wi];
    const int tx = t & 31, ty = t >> 5;
    #pragma unroll
    for (int i = 0; i < 4; ++i)
        T[ty + 8*i][tx] = W[(size_t)(k0 + ty + 8*i) * N + n0 + tx];
    __syncthreads();
    #pragma unroll
    for (int i = 0; i < 4; ++i)
        Wt[(size_t)(n0 + ty + 8*i) * K + k0 + tx] = f2bf(T[tx][ty + 8*i]);
}

// ---------------------------------------------------------------------------
// m97-style bf16 MFMA GEMM: C = act(bn(A @ W) [+ resid]), A:[M][K], Wt:[Nc][K]
// 128x128 tile, BK=32, 4 waves (2x2), fragment-ordered LDS staged via
// global_load_lds (16B/lane). LDS subtile u (16 rows x 32 cols) lives at
// u*512 shorts, slot = lane: row=lane&15, kchunk=lane>>4 -> ds_read_b128 at
// lane*16B is conflict-free and IS the mfma fragment.
// ---------------------------------------------------------------------------
__global__ __launch_bounds__(256, 4) void gemm_bf16(
    const unsigned short* __restrict__ A,
    const unsigned short* __restrict__ Bt,
    const float* __restrict__ bnp,
    const float* __restrict__ residF,
    const unsigned short* __restrict__ residB,
    unsigned short* __restrict__ outB,
    float* __restrict__ outF,
    float* __restrict__ partial,
    int M, int K, int Nc, int kz, int do_relu)
{
    __shared__ unsigned short As[8 * 512];
    __shared__ unsigned short Bs[8 * 512];
    const int t = threadIdx.x;
    const int lane = t & 63, w = t >> 6;
    const int l15 = lane & 15, quad = lane >> 4;
    const int wr = w >> 1, wc = w & 1;
    const int row0 = blockIdx.y * 128;
    const int col0 = blockIdx.x * 128;
    const int kbeg = blockIdx.z * kz;

    floatx4 acc[4][4];
    #pragma unroll
    for (int i = 0; i < 4; ++i)
        #pragma unroll
        for (int j = 0; j < 4; ++j) acc[i][j] = (floatx4){0.f, 0.f, 0.f, 0.f};

    // staging pointers: wave w stages A units {w, w+4}, B units {w, w+4}
    const unsigned short* gA0 = A  + (size_t)(row0 + w*16       + l15) * K + kbeg + quad*8;
    const unsigned short* gA1 = A  + (size_t)(row0 + (w+4)*16   + l15) * K + kbeg + quad*8;
    const unsigned short* gB0 = Bt + (size_t)(col0 + w*16       + l15) * K + kbeg + quad*8;
    const unsigned short* gB1 = Bt + (size_t)(col0 + (w+4)*16   + l15) * K + kbeg + quad*8;
    unsigned short* lA0 = &As[w * 512];
    unsigned short* lA1 = &As[(w + 4) * 512];
    unsigned short* lB0 = &Bs[w * 512];
    unsigned short* lB1 = &Bs[(w + 4) * 512];

    for (int k0 = 0; k0 < kz; k0 += 32) {
        __syncthreads();
        gld_lds16(gA0 + k0, lA0);
        gld_lds16(gA1 + k0, lA1);
        gld_lds16(gB0 + k0, lB0);
        gld_lds16(gB1 + k0, lB1);
        __syncthreads();
        short8 a[4], b[4];
        #pragma unroll
        for (int mt = 0; mt < 4; ++mt) a[mt] = *(const short8*)&As[(wr*4 + mt)*512 + lane*8];
        #pragma unroll
        for (int nt = 0; nt < 4; ++nt) b[nt] = *(const short8*)&Bs[(wc*4 + nt)*512 + lane*8];
        #pragma unroll
        for (int mt = 0; mt < 4; ++mt)
            #pragma unroll
            for (int nt = 0; nt < 4; ++nt)
                acc[mt][nt] = __builtin_amdgcn_mfma_f32_16x16x32_bf16(a[mt], b[nt], acc[mt][nt], 0, 0, 0);
    }

    #pragma unroll
    for (int mt = 0; mt < 4; ++mt) {
        const int rowb = row0 + wr*64 + mt*16 + quad*4;
        #pragma unroll
        for (int nt = 0; nt < 4; ++nt) {
            const int col = col0 + wc*64 + nt*16 + l15;
            floatx4 v = acc[mt][nt];
            if (partial) {
                float* pp = partial + (size_t)blockIdx.z * M * Nc;
                #pragma unroll
                for (int r = 0; r < 4; ++r)
                    pp[(size_t)(rowb + r) * Nc + col] = v[r];
            } else {
                const float g  = bnp[col] * INVC;
                const float be = bnp[Nc + col];
                #pragma unroll
                for (int r = 0; r < 4; ++r) {
                    size_t off = (size_t)(rowb + r) * Nc + col;
                    float v1 = v[r] * g + be;
                    if (residF) v1 += residF[off];
                    if (residB) v1 += bf2f(residB[off]);
                    if (do_relu) v1 = fmaxf(v1, 0.f);
                    if (outB) outB[off] = f2bf(v1);
                    if (outF) outF[off] = v1;
                }
            }
        }
    }
}

// ---------------------------------------------------------------------------
// ffn2 split-K combine: out = relu(bn(sum_z partial) + mo1)
// ---------------------------------------------------------------------------
__global__ __launch_bounds__(256) void ffn2_combine(
    const float* __restrict__ partial, const float* __restrict__ bnp,
    const unsigned short* __restrict__ residB, float* __restrict__ outF)
{
    const int idx = blockIdx.x * 256 + threadIdx.x;   // 131072
    const int col = idx & 127;
    float sum = 0.f;
    #pragma unroll
    for (int z = 0; z < 8; ++z) sum += partial[(size_t)z * 131072 + idx];
    float v = sum * (bnp[col] * INVC) + bnp[128 + col] + bf2f(residB[idx]);
    outF[idx] = fmaxf(v, 0.f);
}

// ---------------------------------------------------------------------------
// Pixel attention: per (b,h,128 L-rows): pret = relu(bn(sigmoid(bn(Q Kt)) V))
// ---------------------------------------------------------------------------
__global__ __launch_bounds__(256) void pix_attn(
    const unsigned short* __restrict__ pqkv,   // [B*4096][512]
    const unsigned short* __restrict__ mqkv,   // [B*128][512]
    const float* __restrict__ bn_sim,          // [2][8]
    const float* __restrict__ bn_ret,          // [2][256]
    unsigned short* __restrict__ pret)         // [B*4096][256]
{
    __shared__ unsigned short Qs[128][40];
    __shared__ unsigned short Ks[128][40];
    __shared__ unsigned short VsT[32][136];
    __shared__ unsigned short Ps[128][136];
    const int t = threadIdx.x;
    const int lane = t & 63, w = t >> 6;
    const int l15 = lane & 15, quad = lane >> 4;
    const int bx = blockIdx.x;
    const int lt = bx & 31, h = (bx >> 5) & 7, b = bx >> 8;
    const int l0 = lt * 128;
    const float simg = bn_sim[h] * INVC, simb = bn_sim[8 + h];

    {
        const int r = t >> 1, half = t & 1;
        uint4 zz = make_uint4(0u, 0u, 0u, 0u);
        const unsigned short* qsrc = pqkv + ((size_t)(b*4096 + l0 + r) << 9) + h*16 + half*8;
        *(uint4*)&Qs[r][half*8] = *(const uint4*)qsrc;
        *(uint4*)&Qs[r][16 + half*8] = zz;
        const unsigned short* ksrc = mqkv + ((size_t)(b*128 + r) << 9) + 128 + h*16 + half*8;
        *(uint4*)&Ks[r][half*8] = *(const uint4*)ksrc;
        *(uint4*)&Ks[r][16 + half*8] = zz;
        const unsigned short* vsrc = mqkv + ((size_t)(b*128 + r) << 9) + 256 + h*32 + half*16;
        uint4 va = *(const uint4*)vsrc;
        uint4 vb = *(const uint4*)(vsrc + 8);
        const int d0 = half * 16;
        VsT[d0+0][r] = (unsigned short)(va.x & 0xffffu); VsT[d0+1][r] = (unsigned short)(va.x >> 16);
        VsT[d0+2][r] = (unsigned short)(va.y & 0xffffu); VsT[d0+3][r] = (unsigned short)(va.y >> 16);
        VsT[d0+4][r] = (unsigned short)(va.z & 0xffffu); VsT[d0+5][r] = (unsigned short)(va.z >> 16);
        VsT[d0+6][r] = (unsigned short)(va.w & 0xffffu); VsT[d0+7][r] = (unsigned short)(va.w >> 16);
        VsT[d0+8][r] = (unsigned short)(vb.x & 0xffffu); VsT[d0+9][r] = (unsigned short)(vb.x >> 16);
        VsT[d0+10][r] = (unsigned short)(vb.y & 0xffffu); VsT[d0+11][r] = (unsigned short)(vb.y >> 16);
        VsT[d0+12][r] = (unsigned short)(vb.z & 0xffffu); VsT[d0+13][r] = (unsigned short)(vb.z >> 16);
        VsT[d0+14][r] = (unsigned short)(vb.w & 0xffffu); VsT[d0+15][r] = (unsigned short)(vb.w >> 16);
    }
    __syncthreads();

    floatx4 z4 = {0.f, 0.f, 0.f, 0.f};
    #pragma unroll
    for (int half = 0; half < 2; ++half) {
        short8 aq = *(const short8*)&Qs[w*32 + half*16 + l15][quad*8];
        #pragma unroll
        for (int nt = 0; nt < 8; ++nt) {
            short8 bk = *(const short8*)&Ks[nt*16 + l15][quad*8];
            floatx4 s = __builtin_amdgcn_mfma_f32_16x16x32_bf16(aq, bk, z4, 0, 0, 0);
            const int rowb = w*32 + half*16 + quad*4;
            #pragma unroll
            for (int r = 0; r < 4; ++r) {
                float x = s[r] * simg + simb;
                float p = 1.f / (1.f + __expf(-x));
                Ps[rowb + r][nt*16 + l15] = f2bf(p);
            }
        }
    }
    __syncthreads();

    #pragma unroll
    for (int half = 0; half < 2; ++half) {
        const int mrow = w*32 + half*16;
        #pragma unroll
        for (int dvt = 0; dvt < 2; ++dvt) {
            floatx4 acc = {0.f, 0.f, 0.f, 0.f};
            #pragma unroll
            for (int ks = 0; ks < 4; ++ks) {
                short8 ap = *(const short8*)&Ps[mrow + l15][ks*32 + quad*8];
                short8 bv = *(const short8*)&VsT[dvt*16 + l15][ks*32 + quad*8];
                acc = __builtin_amdgcn_mfma_f32_16x16x32_bf16(ap, bv, acc, 0, 0, 0);
            }
            const int dv = dvt*16 + l15;
            const float g  = bn_ret[h*32 + dv] * INVC;
            const float be = bn_ret[256 + h*32 + dv];
            #pragma unroll
            for (int r = 0; r < 4; ++r) {
                const int row = l0 + mrow + quad*4 + r;
                float v = fmaxf(acc[r] * g + be, 0.f);
                pret[((size_t)(b*4096 + row) << 8) + h*32 + dv] = f2bf(v);
            }
        }
    }
}

// ---------------------------------------------------------------------------
// Memory attention (flash, MSPLIT-way key split over 33 chunks of 128 keys)
// ---------------------------------------------------------------------------
__global__ __launch_bounds__(256) void mem_attn(
    const unsigned short* __restrict__ mqkv,
    const unsigned short* __restrict__ pqkv,
    const float* __restrict__ bn_sim,
    float* __restrict__ part_acc,   // [64][MSPLIT][128][32]
    float* __restrict__ part_ml)    // [64][MSPLIT][128][2]
{
    __shared__ unsigned short Qs[128][40];
    __shared__ unsigned short Ks[128][40];
    __shared__ unsigned short VsT[32][136];
    __shared__ unsigned short Ps[128][136];
    const int t = threadIdx.x;
    const int lane = t & 63, w = t >> 6;
    const int l15 = lane & 15, quad = lane >> 4;
    const int bx = blockIdx.x;
    const int s = bx & (MSPLIT-1), h = (bx >> 4) & 7, b = bx >> 7;
    const int bh = b*8 + h;
    const float simg = bn_sim[h] * INVC, simb = bn_sim[8 + h];
    const int c0  = (s == 0) ? 0 : (1 + 2*s);
    const int cnt = (s == 0) ? 3 : 2;

    {
        const int r = t >> 1, half = t & 1;
        uint4 zz = make_uint4(0u, 0u, 0u, 0u);
        const unsigned short* qsrc = mqkv + ((size_t)(b*128 + r) << 9) + h*16 + half*8;
        *(uint4*)&Qs[r][half*8] = *(const uint4*)qsrc;
        *(uint4*)&Qs[r][16 + half*8] = zz;
    }

    float m_run[2][4], l_run[2][4];
    floatx4 accpv[2][2];
    #pragma unroll
    for (int i = 0; i < 2; ++i) {
        #pragma unroll
        for (int r = 0; r < 4; ++r) { m_run[i][r] = -1e30f; l_run[i][r] = 0.f; }
        accpv[i][0] = (floatx4){0.f,0.f,0.f,0.f};
        accpv[i][1] = (floatx4){0.f,0.f,0.f,0.f};
    }
    floatx4 z4 = {0.f, 0.f, 0.f, 0.f};

    for (int ci = 0; ci < cnt; ++ci) {
        const int c = c0 + ci;
        __syncthreads();
        {
            const int r = t >> 1, half = t & 1;
            uint4 zz = make_uint4(0u, 0u, 0u, 0u);
            const unsigned short* base = (c < 32)
                ? (pqkv + ((size_t)(b*4096 + c*128 + r) << 9))
                : (mqkv + ((size_t)(b*128 + r) << 9));
            *(uint4*)&Ks[r][half*8] = *(const uint4*)(base + 128 + h*16 + half*8);
            *(uint4*)&Ks[r][16 + half*8] = zz;
            const unsigned short* vsrc = base + 256 + h*32 + half*16;
            uint4 va = *(const uint4*)vsrc;
            uint4 vb = *(const uint4*)(vsrc + 8);
            const int d0 = half * 16;
            VsT[d0+0][r] = (unsigned short)(va.x & 0xffffu); VsT[d0+1][r] = (unsigned short)(va.x >> 16);
            VsT[d0+2][r] = (unsigned short)(va.y & 0xffffu); VsT[d0+3][r] = (unsigned short)(va.y >> 16);
            VsT[d0+4][r] = (unsigned short)(va.z & 0xffffu); VsT[d0+5][r] = (unsigned short)(va.z >> 16);
            VsT[d0+6][r] = (unsigned short)(va.w & 0xffffu); VsT[d0+7][r] = (unsigned short)(va.w >> 16);
            VsT[d0+8][r] = (unsigned short)(vb.x & 0xffffu); VsT[d0+9][r] = (unsigned short)(vb.x >> 16);
            VsT[d0+10][r] = (unsigned short)(vb.y & 0xffffu); VsT[d0+11][r] = (unsigned short)(vb.y >> 16);
            VsT[d0+12][r] = (unsigned short)(vb.z & 0xffffu); VsT[d0+13][r] = (unsigned short)(vb.z >> 16);
            VsT[d0+14][r] = (unsigned short)(vb.w & 0xffffu); VsT[d0+15][r] = (unsigned short)(vb.w >> 16);
        }
        __syncthreads();

        #pragma unroll
        for (int half = 0; half < 2; ++half) {
            float sv[8][4];
            short8 aq = *(const short8*)&Qs[w*32 + half*16 + l15][quad*8];
            #pragma unroll
            for (int nt = 0; nt < 8; ++nt) {
                short8 bk = *(const short8*)&Ks[nt*16 + l15][quad*8];
                floatx4 sr4 = __builtin_amdgcn_mfma_f32_16x16x32_bf16(aq, bk, z4, 0, 0, 0);
                #pragma unroll
                for (int r = 0; r < 4; ++r) sv[nt][r] = sr4[r] * simg + simb;
            }
            const int rowb = w*32 + half*16 + quad*4;
            #pragma unroll
            for (int r = 0; r < 4; ++r) {
                float mx = sv[0][r];
                #pragma unroll
                for (int nt = 1; nt < 8; ++nt) mx = fmaxf(mx, sv[nt][r]);
                mx = fmaxf(mx, __shfl_xor(mx, 1));
                mx = fmaxf(mx, __shfl_xor(mx, 2));
                mx = fmaxf(mx, __shfl_xor(mx, 4));
                mx = fmaxf(mx, __shfl_xor(mx, 8));
                float newm  = fmaxf(m_run[half][r], mx);
                float alpha = __expf(m_run[half][r] - newm);
                m_run[half][r] = newm;
                float lsum = 0.f;
                #pragma unroll
                for (int nt = 0; nt < 8; ++nt) {
                    float p = __expf(sv[nt][r] - newm);
                    lsum += p;
                    Ps[rowb + r][nt*16 + l15] = f2bf(p);
                }
                lsum += __shfl_xor(lsum, 1);
                lsum += __shfl_xor(lsum, 2);
                lsum += __shfl_xor(lsum, 4);
                lsum += __shfl_xor(lsum, 8);
                l_run[half][r] = l_run[half][r] * alpha + lsum;
                accpv[half][0][r] *= alpha;
                accpv[half][1][r] *= alpha;
            }
            __syncthreads();
            const int mrow = w*32 + half*16;
            #pragma unroll
            for (int dvt = 0; dvt < 2; ++dvt) {
                floatx4 a = accpv[half][dvt];
                #pragma unroll
                for (int ks = 0; ks < 4; ++ks) {
                    short8 ap = *(const short8*)&Ps[mrow + l15][ks*32 + quad*8];
                    short8 bv = *(const short8*)&VsT[dvt*16 + l15][ks*32 + quad*8];
                    a = __builtin_amdgcn_mfma_f32_16x16x32_bf16(ap, bv, a, 0, 0, 0);
                }
                accpv[half][dvt] = a;
            }
        }
    }

    #pragma unroll
    for (int half = 0; half < 2; ++half) {
        const int rowb = w*32 + half*16 + quad*4;
        #pragma unroll
        for (int dvt = 0; dvt < 2; ++dvt) {
            const int dv = dvt*16 + l15;
            #pragma unroll
            for (int r = 0; r < 4; ++r)
                part_acc[((size_t)(bh*MSPLIT + s)*128 + rowb + r)*32 + dv] = accpv[half][dvt][r];
        }
        if (l15 == 0) {
            #pragma unroll
            for (int r = 0; r < 4; ++r) {
                size_t o = ((size_t)(bh*MSPLIT + s)*128 + rowb + r) * 2;
                part_ml[o]     = m_run[half][r];
                part_ml[o + 1] = l_run[half][r];
            }
        }
    }
}

__global__ __launch_bounds__(256) void attn_combine(
    const float* __restrict__ part_acc, const float* __restrict__ part_ml,
    const float* __restrict__ bn_ret, unsigned short* __restrict__ mret)
{
    const int idx = blockIdx.x * 256 + threadIdx.x;    // 262144
    const int bh = idx >> 12, rem = idx & 4095;
    const int n = rem >> 5, dv = rem & 31;
    const int h = bh & 7, b = bh >> 3;
    float ms[MSPLIT], ls[MSPLIT];
    float m_g = -1e30f;
    #pragma unroll
    for (int s = 0; s < MSPLIT; ++s) {
        size_t o = ((size_t)(bh*MSPLIT + s)*128 + n) * 2;
        ms[s] = part_ml[o]; ls[s] = part_ml[o + 1];
        m_g = fmaxf(m_g, ms[s]);
    }
    float l_g = 0.f, o_g = 0.f;
    #pragma unroll
    for (int s = 0; s < MSPLIT; ++s) {
        float wgt = __expf(ms[s] - m_g);
        l_g += ls[s] * wgt;
        o_g += part_acc[((size_t)(bh*MSPLIT + s)*128 + n)*32 + dv] * wgt;
    }
    float v = (o_g / l_g) * (bn_ret[h*32 + dv] * INVC) + bn_ret[256 + h*32 + dv];
    v = fmaxf(v, 0.f);
    mret[((size_t)(b*128 + n) << 8) + h*32 + dv] = f2bf(v);
}

// ---------------------------------------------------------------------------
extern "C" void kernel_launch(void* const* d_in, const int* in_sizes, int n_in,
                              void* d_out, int out_size, void* d_ws, size_t ws_size,
                              hipStream_t stream) {
    const float* pixel_input  = (const float*)d_in[0];
    const float* memory_input = (const float*)d_in[1];
    const float* W_mem1    = (const float*)d_in[2];
    const float* bn_mem1   = (const float*)d_in[3];
    const float* W_pix1    = (const float*)d_in[4];
    const float* bn_pix1   = (const float*)d_in[5];
    const float* W_mem_qkv = (const float*)d_in[6];
    const float* bn_mem_qkv= (const float*)d_in[7];
    const float* W_pix_qkv = (const float*)d_in[8];
    const float* bn_pix_qkv= (const float*)d_in[9];
    const float* bn_mem_sim= (const float*)d_in[10];
    const float* bn_mem_ret= (const float*)d_in[11];
    const float* bn_pix_sim= (const float*)d_in[12];
    const float* bn_pix_ret= (const float*)d_in[13];
    const float* W_mem3    = (const float*)d_in[14];
    const float* bn_mem3   = (const float*)d_in[15];
    const float* W_pix3    = (const float*)d_in[16];
    const float* bn_pix3   = (const float*)d_in[17];
    const float* W_ffn1    = (const float*)d_in[18];
    const float* bn_ffn1   = (const float*)d_in[19];
    const float* W_ffn2    = (const float*)d_in[20];
    const float* bn_ffn2   = (const float*)d_in[21];

    char* ws = (char*)d_ws;
    size_t off = 0;
    auto alloc = [&](size_t bytes) -> void* {
        void* p = ws + off; off += (bytes + 255) & ~(size_t)255; return p;
    };
    unsigned short* pixB  = (unsigned short*)alloc((size_t)32768*128*2);
    unsigned short* memB  = (unsigned short*)alloc((size_t)1024*128*2);
    unsigned short* Wt0   = (unsigned short*)alloc((size_t)256*128*2);   // mem1
    unsigned short* Wt1   = (unsigned short*)alloc((size_t)256*128*2);   // pix1
    unsigned short* Wt2   = (unsigned short*)alloc((size_t)512*256*2);   // mem_qkv
    unsigned short* Wt3   = (unsigned short*)alloc((size_t)512*256*2);   // pix_qkv
    unsigned short* Wt4   = (unsigned short*)alloc((size_t)128*256*2);   // mem3
    unsigned short* Wt5   = (unsigned short*)alloc((size_t)128*256*2);   // pix3
    unsigned short* Wt6   = (unsigned short*)alloc((size_t)2048*128*2);  // ffn1
    unsigned short* Wt7   = (unsigned short*)alloc((size_t)128*2048*2);  // ffn2
    unsigned short* memA  = (unsigned short*)alloc((size_t)1024*256*2);
    unsigned short* mqkvB = (unsigned short*)alloc((size_t)1024*512*2);
    unsigned short* pixA  = (unsigned short*)alloc((size_t)32768*256*2);
    unsigned short* pqkvB = (unsigned short*)alloc((size_t)32768*512*2);
    float* part_acc = (float*)alloc((size_t)64*MSPLIT*128*32*4);
    float* part_ml  = (float*)alloc((size_t)64*MSPLIT*128*2*4);
    unsigned short* mretB = (unsigned short*)alloc((size_t)1024*256*2);
    unsigned short* mo1B  = (unsigned short*)alloc((size_t)1024*128*2);
    unsigned short* ffnB  = (unsigned short*)alloc((size_t)1024*2048*2);
    float* part_ffn = (float*)alloc((size_t)8*1024*128*4);
    unsigned short* pretB = (unsigned short*)alloc((size_t)32768*256*2);

    float* out_pix = (float*)d_out;
    float* out_mem = (float*)d_out + (size_t)8*4096*128;

    PrepPtrs P;
    P.src_pix = pixel_input; P.src_mem = memory_input;
    P.dst_pix = pixB; P.dst_mem = memB;
    P.W[0]=W_mem1; P.W[1]=W_pix1; P.W[2]=W_mem_qkv; P.W[3]=W_pix_qkv;
    P.W[4]=W_mem3; P.W[5]=W_pix3; P.W[6]=W_ffn1;    P.W[7]=W_ffn2;
    P.Wt[0]=Wt0; P.Wt[1]=Wt1; P.Wt[2]=Wt2; P.Wt[3]=Wt3;
    P.Wt[4]=Wt4; P.Wt[5]=Wt5; P.Wt[6]=Wt6; P.Wt[7]=Wt7;

    dim3 blk(256);
    prep_kernel<<<5120, blk, 0, stream>>>(P);

    // mem = relu(bn(memory @ W_mem1))          [1024 x 256, K=128]
    gemm_bf16<<<dim3(2,8,1), blk, 0, stream>>>(memB, Wt0, bn_mem1, nullptr, nullptr,
        memA, nullptr, nullptr, 1024, 128, 256, 128, 1);
    // pix = relu(bn(pixel @ W_pix1))           [32768 x 256, K=128]
    gemm_bf16<<<dim3(2,256,1), blk, 0, stream>>>(pixB, Wt1, bn_pix1, nullptr, nullptr,
        pixA, nullptr, nullptr, 32768, 128, 256, 128, 1);
    // mqkv = bn(mem @ W_mem_qkv)               [1024 x 512, K=256]
    gemm_bf16<<<dim3(4,8,1), blk, 0, stream>>>(memA, Wt2, bn_mem_qkv, nullptr, nullptr,
        mqkvB, nullptr, nullptr, 1024, 256, 512, 256, 0);
    // pqkv = bn(pix @ W_pix_qkv)               [32768 x 512, K=256]
    gemm_bf16<<<dim3(4,256,1), blk, 0, stream>>>(pixA, Wt3, bn_pix_qkv, nullptr, nullptr,
        pqkvB, nullptr, nullptr, 32768, 256, 512, 256, 0);

    // memory attention (flash, MSPLIT-way key split) + combine
    mem_attn<<<64*MSPLIT, blk, 0, stream>>>(mqkvB, pqkvB, bn_mem_sim, part_acc, part_ml);
    attn_combine<<<1024, blk, 0, stream>>>(part_acc, part_ml, bn_mem_ret, mretB);

    // mem_out1 = relu(memory + bn(mret @ W_mem3))   [1024 x 128, K=256]
    gemm_bf16<<<dim3(1,8,1), blk, 0, stream>>>(mretB, Wt4, bn_mem3, memory_input, nullptr,
        mo1B, nullptr, nullptr, 1024, 256, 128, 256, 1);
    // ffn = relu(bn(mem_out1 @ W_ffn1))        [1024 x 2048, K=128]
    gemm_bf16<<<dim3(16,8,1), blk, 0, stream>>>(mo1B, Wt6, bn_ffn1, nullptr, nullptr,
        ffnB, nullptr, nullptr, 1024, 128, 2048, 128, 1);
    // ffn2 partial (split-K=8)                 [1024 x 128, K=2048]
    gemm_bf16<<<dim3(1,8,8), blk, 0, stream>>>(ffnB, Wt7, nullptr, nullptr, nullptr,
        nullptr, nullptr, part_ffn, 1024, 2048, 128, 256, 0);
    ffn2_combine<<<512, blk, 0, stream>>>(part_ffn, bn_ffn2, mo1B, out_mem);

    // pixel attention
    pix_attn<<<2048, blk, 0, stream>>>(pqkvB, mqkvB, bn_pix_sim, bn_pix_ret, pretB);
    // pix_out = relu(pixel + bn(pret @ W_pix3))    [32768 x 128, K=256]
    gemm_bf16<<<dim3(1,256,1), blk, 0, stream>>>(pretB, Wt5, bn_pix3, pixel_input, nullptr,
        nullptr, out_pix, nullptr, 32768, 256, 128, 256, 1);
}

// Round 4
// 283.668 us; speedup vs baseline: 1.1657x; 1.1657x over previous
//
#include <hip/hip_runtime.h>

typedef __attribute__((ext_vector_type(8))) short short8;
typedef __attribute__((ext_vector_type(4))) float floatx4;

#define INVC 0.9995003746877732f
#define MSPLIT 8

__device__ __forceinline__ unsigned short f2bf(float f) {
    union { float f; unsigned int u; } c; c.f = f;
    unsigned int r = c.u + 0x7fffu + ((c.u >> 16) & 1u);
    return (unsigned short)(r >> 16);
}
__device__ __forceinline__ float bf2f(unsigned short u) {
    union { unsigned int u; float f; } c; c.u = ((unsigned int)u) << 16;
    return c.f;
}
__device__ __forceinline__ void gld_lds16(const unsigned short* g, unsigned short* l) {
    __builtin_amdgcn_global_load_lds(
        (const __attribute__((address_space(1))) unsigned int*)g,
        (__attribute__((address_space(3))) unsigned int*)l, 16, 0, 0);
}
// A/B-frag index helper: element (row in 16-row unit, k) -> offset in frag unit
// layout: unit[kc]: lane = row + 16*((k>>3)&3), byte j = k&7; unit stride 512 shorts
__device__ __forceinline__ int fidx(int row, int k) {
    return (k >> 5) * 512 + (row + 16 * ((k >> 3) & 3)) * 8 + (k & 7);
}

// ---------------------------------------------------------------------------
// Prep: fp32->bf16 cast of pixel input + transpose-cast of 8 weight matrices
// ---------------------------------------------------------------------------
struct PrepPtrs {
    const float* src_pix;
    unsigned short* dst_pix;
    const float* W[8]; unsigned short* Wt[8];
};

__global__ __launch_bounds__(256) void prep_kernel(PrepPtrs P) {
    __shared__ float T[32][33];
    const int bid = blockIdx.x, t = threadIdx.x;
    if (bid < 4096) {
        int i = bid * 1024 + t * 4;
        float4 v = *(const float4*)(P.src_pix + i);
        unsigned long long pk = (unsigned long long)f2bf(v.x)
            | ((unsigned long long)f2bf(v.y) << 16)
            | ((unsigned long long)f2bf(v.z) << 32)
            | ((unsigned long long)f2bf(v.w) << 48);
        *(unsigned long long*)(P.dst_pix + i) = pk;
        return;
    }
    int rel = bid - 4096;
    const int KD[8]  = {128,128,256,256,256,256,128,2048};
    const int ND[8]  = {256,256,512,512,128,128,2048,128};
    const int CNT[8] = {32,32,128,128,32,32,256,256};
    int wi = 0;
    #pragma unroll
    for (int k = 0; k < 8; ++k) { if (rel >= CNT[k] && wi == k) { rel -= CNT[k]; wi = k + 1; } }
    const int K = KD[wi], N = ND[wi];
    const int ntn = N >> 5;
    const int tn = rel % ntn, tk = rel / ntn;
    const int n0 = tn * 32, k0 = tk * 32;
    const float* W = P.W[wi];
    unsigned short* Wt = P.Wt[wi];
    const int tx = t & 31, ty = t >> 5;
    #pragma unroll
    for (int i = 0; i < 4; ++i)
        T[ty + 8*i][tx] = W[(size_t)(k0 + ty + 8*i) * N + n0 + tx];
    __syncthreads();
    #pragma unroll
    for (int i = 0; i < 4; ++i)
        Wt[(size_t)(n0 + ty + 8*i) * K + k0 + tx] = f2bf(T[tx][ty + 8*i]);
}

// ---------------------------------------------------------------------------
// m97-style bf16 MFMA GEMM (pix path): C = act(bn(A @ W) [+ residF])
// ---------------------------------------------------------------------------
__global__ __launch_bounds__(256, 4) void gemm_bf16(
    const unsigned short* __restrict__ A,
    const unsigned short* __restrict__ Bt,
    const float* __restrict__ bnp,
    const float* __restrict__ residF,
    unsigned short* __restrict__ outB,
    float* __restrict__ outF,
    int M, int K, int Nc, int do_relu)
{
    __shared__ unsigned short As[8 * 512];
    __shared__ unsigned short Bs[8 * 512];
    const int t = threadIdx.x;
    const int lane = t & 63, w = t >> 6;
    const int l15 = lane & 15, quad = lane >> 4;
    const int wr = w >> 1, wc = w & 1;
    const int row0 = blockIdx.y * 128;
    const int col0 = blockIdx.x * 128;

    floatx4 acc[4][4];
    #pragma unroll
    for (int i = 0; i < 4; ++i)
        #pragma unroll
        for (int j = 0; j < 4; ++j) acc[i][j] = (floatx4){0.f, 0.f, 0.f, 0.f};

    const unsigned short* gA0 = A  + (size_t)(row0 + w*16     + l15) * K + quad*8;
    const unsigned short* gA1 = A  + (size_t)(row0 + (w+4)*16 + l15) * K + quad*8;
    const unsigned short* gB0 = Bt + (size_t)(col0 + w*16     + l15) * K + quad*8;
    const unsigned short* gB1 = Bt + (size_t)(col0 + (w+4)*16 + l15) * K + quad*8;
    unsigned short* lA0 = &As[w * 512];
    unsigned short* lA1 = &As[(w + 4) * 512];
    unsigned short* lB0 = &Bs[w * 512];
    unsigned short* lB1 = &Bs[(w + 4) * 512];

    for (int k0 = 0; k0 < K; k0 += 32) {
        __syncthreads();
        gld_lds16(gA0 + k0, lA0);
        gld_lds16(gA1 + k0, lA1);
        gld_lds16(gB0 + k0, lB0);
        gld_lds16(gB1 + k0, lB1);
        __syncthreads();
        short8 a[4], b[4];
        #pragma unroll
        for (int mt = 0; mt < 4; ++mt) a[mt] = *(const short8*)&As[(wr*4 + mt)*512 + lane*8];
        #pragma unroll
        for (int nt = 0; nt < 4; ++nt) b[nt] = *(const short8*)&Bs[(wc*4 + nt)*512 + lane*8];
        #pragma unroll
        for (int mt = 0; mt < 4; ++mt)
            #pragma unroll
            for (int nt = 0; nt < 4; ++nt)
                acc[mt][nt] = __builtin_amdgcn_mfma_f32_16x16x32_bf16(a[mt], b[nt], acc[mt][nt], 0, 0, 0);
    }

    #pragma unroll
    for (int mt = 0; mt < 4; ++mt) {
        const int rowb = row0 + wr*64 + mt*16 + quad*4;
        #pragma unroll
        for (int nt = 0; nt < 4; ++nt) {
            const int col = col0 + wc*64 + nt*16 + l15;
            floatx4 v = acc[mt][nt];
            const float g  = bnp[col] * INVC;
            const float be = bnp[Nc + col];
            #pragma unroll
            for (int r = 0; r < 4; ++r) {
                size_t off = (size_t)(rowb + r) * Nc + col;
                float v1 = v[r] * g + be;
                if (residF) v1 += residF[off];
                if (do_relu) v1 = fmaxf(v1, 0.f);
                if (outB) outB[off] = f2bf(v1);
                if (outF) outF[off] = v1;
            }
        }
    }
}

// ---------------------------------------------------------------------------
// mem_fused: cast + mem1 + mqkv, 64 blocks x 16 rows, weights from L2
// ---------------------------------------------------------------------------
__global__ __launch_bounds__(256) void mem_fused(
    const float* __restrict__ memory_input,
    const unsigned short* __restrict__ Wt0, const float* __restrict__ bn1,
    const unsigned short* __restrict__ Wt2, const float* __restrict__ bnq,
    unsigned short* __restrict__ mqkv)
{
    __shared__ unsigned short A0[4*512];
    __shared__ unsigned short A1[8*512];
    const int t = threadIdx.x;
    const int lane = t & 63, w = t >> 6;
    const int l15 = lane & 15, quad = lane >> 4;
    const int g0 = blockIdx.x * 16;

    {   // cast 16x128 fp32 -> A-frag (K=128)
        const int row = t >> 4;
        const int c0 = (t & 15) * 8;
        const float* src = memory_input + (size_t)(g0 + row) * 128 + c0;
        float4 v0 = *(const float4*)src;
        float4 v1 = *(const float4*)(src + 4);
        float vv[8] = {v0.x, v0.y, v0.z, v0.w, v1.x, v1.y, v1.z, v1.w};
        #pragma unroll
        for (int e = 0; e < 8; ++e)
            A0[fidx(row, c0 + e)] = f2bf(vv[e]);
    }
    __syncthreads();

    // mem1: M=16, N=256, K=128
    #pragma unroll
    for (int i = 0; i < 4; ++i) {
        const int n0 = (w*4 + i) * 16;
        floatx4 acc = {0.f,0.f,0.f,0.f};
        #pragma unroll
        for (int kc = 0; kc < 4; ++kc) {
            short8 a = *(const short8*)&A0[kc*512 + lane*8];
            short8 bfr = *(const short8*)&Wt0[(size_t)(n0 + l15)*128 + kc*32 + quad*8];
            acc = __builtin_amdgcn_mfma_f32_16x16x32_bf16(a, bfr, acc, 0, 0, 0);
        }
        const int col = n0 + l15;
        const float g = bn1[col] * INVC, be = bn1[256 + col];
        #pragma unroll
        for (int r = 0; r < 4; ++r) {
            const int row = quad*4 + r;
            float v = fmaxf(acc[r]*g + be, 0.f);
            A1[fidx(row, col)] = f2bf(v);
        }
    }
    __syncthreads();

    // mqkv: M=16, N=512, K=256
    #pragma unroll
    for (int i = 0; i < 8; ++i) {
        const int n0 = w*128 + i*16;
        floatx4 acc = {0.f,0.f,0.f,0.f};
        #pragma unroll
        for (int kc = 0; kc < 8; ++kc) {
            short8 a = *(const short8*)&A1[kc*512 + lane*8];
            short8 bfr = *(const short8*)&Wt2[(size_t)(n0 + l15)*256 + kc*32 + quad*8];
            acc = __builtin_amdgcn_mfma_f32_16x16x32_bf16(a, bfr, acc, 0, 0, 0);
        }
        const int col = n0 + l15;
        const float g = bnq[col] * INVC, be = bnq[512 + col];
        #pragma unroll
        for (int r = 0; r < 4; ++r) {
            const int row = quad*4 + r;
            mqkv[(size_t)(g0 + row)*512 + col] = f2bf(acc[r]*g + be);
        }
    }
}

// ---------------------------------------------------------------------------
// ffn_fused: attn_combine + mem3(+resid,relu) + ffn1 + ffn2(+resid,relu)
// 64 blocks x 16 rows; weights (1.1 MB total) streamed from L2
// ---------------------------------------------------------------------------
__global__ __launch_bounds__(256) void ffn_fused(
    const float* __restrict__ part_acc, const float* __restrict__ part_ml,
    const float* __restrict__ bn_ret,
    const unsigned short* __restrict__ Wt4, const float* __restrict__ bn3,
    const float* __restrict__ memory_input,
    const unsigned short* __restrict__ Wt6, const float* __restrict__ bnf1,
    const unsigned short* __restrict__ Wt7, const float* __restrict__ bnf2,
    float* __restrict__ out_mem)
{
    __shared__ unsigned short mretA[8*512];
    __shared__ unsigned short moA[4*512];
    __shared__ unsigned short fA[64*512];
    const int t = threadIdx.x;
    const int lane = t & 63, w = t >> 6;
    const int l15 = lane & 15, quad = lane >> 4;
    const int g0 = blockIdx.x * 16;
    const int b = g0 >> 7;
    const int nbase = g0 & 127;

    {   // phase 0: flash combine -> mretA (16 x 256)
        const int row = t >> 4;
        const int c0 = (t & 15) * 16;          // 16-col span, single head
        const int h = c0 >> 5;
        const int n = nbase + row;
        const int bh = b*8 + h;
        float ms[MSPLIT], ls[MSPLIT], m_g = -1e30f;
        #pragma unroll
        for (int s = 0; s < MSPLIT; ++s) {
            size_t o = ((size_t)(bh*MSPLIT + s)*128 + n)*2;
            ms[s] = part_ml[o]; ls[s] = part_ml[o+1];
            m_g = fmaxf(m_g, ms[s]);
        }
        float l_g = 0.f;
        float og[16];
        #pragma unroll
        for (int e = 0; e < 16; ++e) og[e] = 0.f;
        #pragma unroll
        for (int s = 0; s < MSPLIT; ++s) {
            float wgt = __expf(ms[s] - m_g);
            l_g += ls[s] * wgt;
            const float* pa = part_acc + ((size_t)(bh*MSPLIT + s)*128 + n)*32 + (c0 & 31);
            #pragma unroll
            for (int e = 0; e < 16; e += 4) {
                float4 v = *(const float4*)(pa + e);
                og[e]   += v.x*wgt; og[e+1] += v.y*wgt;
                og[e+2] += v.z*wgt; og[e+3] += v.w*wgt;
            }
        }
        float invl = 1.f / l_g;
        #pragma unroll
        for (int e = 0; e < 16; ++e) {
            int col = c0 + e;
            int dv = col & 31;
            float v = og[e]*invl*(bn_ret[h*32+dv]*INVC) + bn_ret[256 + h*32 + dv];
            mretA[fidx(row, col)] = f2bf(fmaxf(v, 0.f));
        }
    }
    __syncthreads();

    // phase 1: mem3 M=16,N=128,K=256; keep mo in regs for ffn2 residual
    floatx4 mo[2];
    #pragma unroll
    for (int i = 0; i < 2; ++i) {
        const int n0 = (w*2 + i) * 16;
        floatx4 acc = {0.f,0.f,0.f,0.f};
        #pragma unroll
        for (int kc = 0; kc < 8; ++kc) {
            short8 a = *(const short8*)&mretA[kc*512 + lane*8];
            short8 bfr = *(const short8*)&Wt4[(size_t)(n0 + l15)*256 + kc*32 + quad*8];
            acc = __builtin_amdgcn_mfma_f32_16x16x32_bf16(a, bfr, acc, 0, 0, 0);
        }
        const int col = n0 + l15;
        const float g = bn3[col]*INVC, be = bn3[128 + col];
        #pragma unroll
        for (int r = 0; r < 4; ++r) {
            const int row = quad*4 + r;
            float v = acc[r]*g + be + memory_input[(size_t)(g0 + row)*128 + col];
            v = fmaxf(v, 0.f);
            mo[i][r] = v;
            moA[fidx(row, col)] = f2bf(v);
        }
    }
    __syncthreads();

    // phase 2: ffn1 M=16,N=2048,K=128 -> fA
    for (int nt = 0; nt < 32; ++nt) {
        const int n0 = w*512 + nt*16;
        floatx4 acc = {0.f,0.f,0.f,0.f};
        #pragma unroll
        for (int kc = 0; kc < 4; ++kc) {
            short8 a = *(const short8*)&moA[kc*512 + lane*8];
            short8 bfr = *(const short8*)&Wt6[(size_t)(n0 + l15)*128 + kc*32 + quad*8];
            acc = __builtin_amdgcn_mfma_f32_16x16x32_bf16(a, bfr, acc, 0, 0, 0);
        }
        const int col = n0 + l15;
        const float g = bnf1[col]*INVC, be = bnf1[2048 + col];
        #pragma unroll
        for (int r = 0; r < 4; ++r) {
            const int row = quad*4 + r;
            fA[fidx(row, col)] = f2bf(fmaxf(acc[r]*g + be, 0.f));
        }
    }
    __syncthreads();

    // phase 3: ffn2 M=16,N=128,K=2048 (+ mo resid from regs)
    #pragma unroll
    for (int i = 0; i < 2; ++i) {
        const int n0 = (w*2 + i) * 16;
        floatx4 acc = {0.f,0.f,0.f,0.f};
        #pragma unroll 8
        for (int kc = 0; kc < 64; ++kc) {
            short8 a = *(const short8*)&fA[kc*512 + lane*8];
            short8 bfr = *(const short8*)&Wt7[(size_t)(n0 + l15)*2048 + kc*32 + quad*8];
            acc = __builtin_amdgcn_mfma_f32_16x16x32_bf16(a, bfr, acc, 0, 0, 0);
        }
        const int col = n0 + l15;
        const float g = bnf2[col]*INVC, be = bnf2[128 + col];
        #pragma unroll
        for (int r = 0; r < 4; ++r) {
            const int row = quad*4 + r;
            float v = fmaxf(acc[r]*g + be + mo[i][r], 0.f);
            out_mem[(size_t)(g0 + row)*128 + col] = v;
        }
    }
}

// ---------------------------------------------------------------------------
// Pixel attention (unchanged)
// ---------------------------------------------------------------------------
__global__ __launch_bounds__(256) void pix_attn(
    const unsigned short* __restrict__ pqkv,
    const unsigned short* __restrict__ mqkv,
    const float* __restrict__ bn_sim,
    const float* __restrict__ bn_ret,
    unsigned short* __restrict__ pret)
{
    __shared__ unsigned short Qs[128][40];
    __shared__ unsigned short Ks[128][40];
    __shared__ unsigned short VsT[32][136];
    __shared__ unsigned short Ps[128][136];
    const int t = threadIdx.x;
    const int lane = t & 63, w = t >> 6;
    const int l15 = lane & 15, quad = lane >> 4;
    const int bx = blockIdx.x;
    const int lt = bx & 31, h = (bx >> 5) & 7, b = bx >> 8;
    const int l0 = lt * 128;
    const float simg = bn_sim[h] * INVC, simb = bn_sim[8 + h];

    {
        const int r = t >> 1, half = t & 1;
        uint4 zz = make_uint4(0u, 0u, 0u, 0u);
        const unsigned short* qsrc = pqkv + ((size_t)(b*4096 + l0 + r) << 9) + h*16 + half*8;
        *(uint4*)&Qs[r][half*8] = *(const uint4*)qsrc;
        *(uint4*)&Qs[r][16 + half*8] = zz;
        const unsigned short* ksrc = mqkv + ((size_t)(b*128 + r) << 9) + 128 + h*16 + half*8;
        *(uint4*)&Ks[r][half*8] = *(const uint4*)ksrc;
        *(uint4*)&Ks[r][16 + half*8] = zz;
        const unsigned short* vsrc = mqkv + ((size_t)(b*128 + r) << 9) + 256 + h*32 + half*16;
        uint4 va = *(const uint4*)vsrc;
        uint4 vb = *(const uint4*)(vsrc + 8);
        const int d0 = half * 16;
        VsT[d0+0][r] = (unsigned short)(va.x & 0xffffu); VsT[d0+1][r] = (unsigned short)(va.x >> 16);
        VsT[d0+2][r] = (unsigned short)(va.y & 0xffffu); VsT[d0+3][r] = (unsigned short)(va.y >> 16);
        VsT[d0+4][r] = (unsigned short)(va.z & 0xffffu); VsT[d0+5][r] = (unsigned short)(va.z >> 16);
        VsT[d0+6][r] = (unsigned short)(va.w & 0xffffu); VsT[d0+7][r] = (unsigned short)(va.w >> 16);
        VsT[d0+8][r] = (unsigned short)(vb.x & 0xffffu); VsT[d0+9][r] = (unsigned short)(vb.x >> 16);
        VsT[d0+10][r] = (unsigned short)(vb.y & 0xffffu); VsT[d0+11][r] = (unsigned short)(vb.y >> 16);
        VsT[d0+12][r] = (unsigned short)(vb.z & 0xffffu); VsT[d0+13][r] = (unsigned short)(vb.z >> 16);
        VsT[d0+14][r] = (unsigned short)(vb.w & 0xffffu); VsT[d0+15][r] = (unsigned short)(vb.w >> 16);
    }
    __syncthreads();

    floatx4 z4 = {0.f, 0.f, 0.f, 0.f};
    #pragma unroll
    for (int half = 0; half < 2; ++half) {
        short8 aq = *(const short8*)&Qs[w*32 + half*16 + l15][quad*8];
        #pragma unroll
        for (int nt = 0; nt < 8; ++nt) {
            short8 bk = *(const short8*)&Ks[nt*16 + l15][quad*8];
            floatx4 s = __builtin_amdgcn_mfma_f32_16x16x32_bf16(aq, bk, z4, 0, 0, 0);
            const int rowb = w*32 + half*16 + quad*4;
            #pragma unroll
            for (int r = 0; r < 4; ++r) {
                float x = s[r] * simg + simb;
                float p = 1.f / (1.f + __expf(-x));
                Ps[rowb + r][nt*16 + l15] = f2bf(p);
            }
        }
    }
    __syncthreads();

    #pragma unroll
    for (int half = 0; half < 2; ++half) {
        const int mrow = w*32 + half*16;
        #pragma unroll
        for (int dvt = 0; dvt < 2; ++dvt) {
            floatx4 acc = {0.f, 0.f, 0.f, 0.f};
            #pragma unroll
            for (int ks = 0; ks < 4; ++ks) {
                short8 ap = *(const short8*)&Ps[mrow + l15][ks*32 + quad*8];
                short8 bv = *(const short8*)&VsT[dvt*16 + l15][ks*32 + quad*8];
                acc = __builtin_amdgcn_mfma_f32_16x16x32_bf16(ap, bv, acc, 0, 0, 0);
            }
            const int dv = dvt*16 + l15;
            const float g  = bn_ret[h*32 + dv] * INVC;
            const float be = bn_ret[256 + h*32 + dv];
            #pragma unroll
            for (int r = 0; r < 4; ++r) {
                const int row = l0 + mrow + quad*4 + r;
                float v = fmaxf(acc[r] * g + be, 0.f);
                pret[((size_t)(b*4096 + row) << 8) + h*32 + dv] = f2bf(v);
            }
        }
    }
}

// ---------------------------------------------------------------------------
// Memory attention (flash, MSPLIT-way key split over 33 chunks of 128 keys)
// ---------------------------------------------------------------------------
__global__ __launch_bounds__(256) void mem_attn(
    const unsigned short* __restrict__ mqkv,
    const unsigned short* __restrict__ pqkv,
    const float* __restrict__ bn_sim,
    float* __restrict__ part_acc,   // [64][MSPLIT][128][32]
    float* __restrict__ part_ml)    // [64][MSPLIT][128][2]
{
    __shared__ unsigned short Qs[128][40];
    __shared__ unsigned short Ks[128][40];
    __shared__ unsigned short VsT[32][136];
    __shared__ unsigned short Ps[128][136];
    const int t = threadIdx.x;
    const int lane = t & 63, w = t >> 6;
    const int l15 = lane & 15, quad = lane >> 4;
    const int bx = blockIdx.x;
    const int s = bx & (MSPLIT-1), h = (bx >> 3) & 7, b = bx >> 6;
    const int bh = b*8 + h;
    const float simg = bn_sim[h] * INVC, simb = bn_sim[8 + h];
    const int c0  = (s == 0) ? 0 : (4*s + 1);
    const int cnt = (s == 0) ? 5 : 4;

    {
        const int r = t >> 1, half = t & 1;
        uint4 zz = make_uint4(0u, 0u, 0u, 0u);
        const unsigned short* qsrc = mqkv + ((size_t)(b*128 + r) << 9) + h*16 + half*8;
        *(uint4*)&Qs[r][half*8] = *(const uint4*)qsrc;
        *(uint4*)&Qs[r][16 + half*8] = zz;
    }

    float m_run[2][4], l_run[2][4];
    floatx4 accpv[2][2];
    #pragma unroll
    for (int i = 0; i < 2; ++i) {
        #pragma unroll
        for (int r = 0; r < 4; ++r) { m_run[i][r] = -1e30f; l_run[i][r] = 0.f; }
        accpv[i][0] = (floatx4){0.f,0.f,0.f,0.f};
        accpv[i][1] = (floatx4){0.f,0.f,0.f,0.f};
    }
    floatx4 z4 = {0.f, 0.f, 0.f, 0.f};

    for (int ci = 0; ci < cnt; ++ci) {
        const int c = c0 + ci;
        __syncthreads();
        {
            const int r = t >> 1, half = t & 1;
            uint4 zz = make_uint4(0u, 0u, 0u, 0u);
            const unsigned short* base = (c < 32)
                ? (pqkv + ((size_t)(b*4096 + c*128 + r) << 9))
                : (mqkv + ((size_t)(b*128 + r) << 9));
            *(uint4*)&Ks[r][half*8] = *(const uint4*)(base + 128 + h*16 + half*8);
            *(uint4*)&Ks[r][16 + half*8] = zz;
            const unsigned short* vsrc = base + 256 + h*32 + half*16;
            uint4 va = *(const uint4*)vsrc;
            uint4 vb = *(const uint4*)(vsrc + 8);
            const int d0 = half * 16;
            VsT[d0+0][r] = (unsigned short)(va.x & 0xffffu); VsT[d0+1][r] = (unsigned short)(va.x >> 16);
            VsT[d0+2][r] = (unsigned short)(va.y & 0xffffu); VsT[d0+3][r] = (unsigned short)(va.y >> 16);
            VsT[d0+4][r] = (unsigned short)(va.z & 0xffffu); VsT[d0+5][r] = (unsigned short)(va.z >> 16);
            VsT[d0+6][r] = (unsigned short)(va.w & 0xffffu); VsT[d0+7][r] = (unsigned short)(va.w >> 16);
            VsT[d0+8][r] = (unsigned short)(vb.x & 0xffffu); VsT[d0+9][r] = (unsigned short)(vb.x >> 16);
            VsT[d0+10][r] = (unsigned short)(vb.y & 0xffffu); VsT[d0+11][r] = (unsigned short)(vb.y >> 16);
            VsT[d0+12][r] = (unsigned short)(vb.z & 0xffffu); VsT[d0+13][r] = (unsigned short)(vb.z >> 16);
            VsT[d0+14][r] = (unsigned short)(vb.w & 0xffffu); VsT[d0+15][r] = (unsigned short)(vb.w >> 16);
        }
        __syncthreads();

        #pragma unroll
        for (int half = 0; half < 2; ++half) {
            float sv[8][4];
            short8 aq = *(const short8*)&Qs[w*32 + half*16 + l15][quad*8];
            #pragma unroll
            for (int nt = 0; nt < 8; ++nt) {
                short8 bk = *(const short8*)&Ks[nt*16 + l15][quad*8];
                floatx4 sr4 = __builtin_amdgcn_mfma_f32_16x16x32_bf16(aq, bk, z4, 0, 0, 0);
                #pragma unroll
                for (int r = 0; r < 4; ++r) sv[nt][r] = sr4[r] * simg + simb;
            }
            const int rowb = w*32 + half*16 + quad*4;
            #pragma unroll
            for (int r = 0; r < 4; ++r) {
                float mx = sv[0][r];
                #pragma unroll
                for (int nt = 1; nt < 8; ++nt) mx = fmaxf(mx, sv[nt][r]);
                mx = fmaxf(mx, __shfl_xor(mx, 1));
                mx = fmaxf(mx, __shfl_xor(mx, 2));
                mx = fmaxf(mx, __shfl_xor(mx, 4));
                mx = fmaxf(mx, __shfl_xor(mx, 8));
                float newm  = fmaxf(m_run[half][r], mx);
                float alpha = __expf(m_run[half][r] - newm);
                m_run[half][r] = newm;
                float lsum = 0.f;
                #pragma unroll
                for (int nt = 0; nt < 8; ++nt) {
                    float p = __expf(sv[nt][r] - newm);
                    lsum += p;
                    Ps[rowb + r][nt*16 + l15] = f2bf(p);
                }
                lsum += __shfl_xor(lsum, 1);
                lsum += __shfl_xor(lsum, 2);
                lsum += __shfl_xor(lsum, 4);
                lsum += __shfl_xor(lsum, 8);
                l_run[half][r] = l_run[half][r] * alpha + lsum;
                accpv[half][0][r] *= alpha;
                accpv[half][1][r] *= alpha;
            }
            __syncthreads();
            const int mrow = w*32 + half*16;
            #pragma unroll
            for (int dvt = 0; dvt < 2; ++dvt) {
                floatx4 a = accpv[half][dvt];
                #pragma unroll
                for (int ks = 0; ks < 4; ++ks) {
                    short8 ap = *(const short8*)&Ps[mrow + l15][ks*32 + quad*8];
                    short8 bv = *(const short8*)&VsT[dvt*16 + l15][ks*32 + quad*8];
                    a = __builtin_amdgcn_mfma_f32_16x16x32_bf16(ap, bv, a, 0, 0, 0);
                }
                accpv[half][dvt] = a;
            }
        }
    }

    #pragma unroll
    for (int half = 0; half < 2; ++half) {
        const int rowb = w*32 + half*16 + quad*4;
        #pragma unroll
        for (int dvt = 0; dvt < 2; ++dvt) {
            const int dv = dvt*16 + l15;
            #pragma unroll
            for (int r = 0; r < 4; ++r)
                part_acc[((size_t)(bh*MSPLIT + s)*128 + rowb + r)*32 + dv] = accpv[half][dvt][r];
        }
        if (l15 == 0) {
            #pragma unroll
            for (int r = 0; r < 4; ++r) {
                size_t o = ((size_t)(bh*MSPLIT + s)*128 + rowb + r) * 2;
                part_ml[o]     = m_run[half][r];
                part_ml[o + 1] = l_run[half][r];
            }
        }
    }
}

// ---------------------------------------------------------------------------
extern "C" void kernel_launch(void* const* d_in, const int* in_sizes, int n_in,
                              void* d_out, int out_size, void* d_ws, size_t ws_size,
                              hipStream_t stream) {
    const float* pixel_input  = (const float*)d_in[0];
    const float* memory_input = (const float*)d_in[1];
    const float* W_mem1    = (const float*)d_in[2];
    const float* bn_mem1   = (const float*)d_in[3];
    const float* W_pix1    = (const float*)d_in[4];
    const float* bn_pix1   = (const float*)d_in[5];
    const float* W_mem_qkv = (const float*)d_in[6];
    const float* bn_mem_qkv= (const float*)d_in[7];
    const float* W_pix_qkv = (const float*)d_in[8];
    const float* bn_pix_qkv= (const float*)d_in[9];
    const float* bn_mem_sim= (const float*)d_in[10];
    const float* bn_mem_ret= (const float*)d_in[11];
    const float* bn_pix_sim= (const float*)d_in[12];
    const float* bn_pix_ret= (const float*)d_in[13];
    const float* W_mem3    = (const float*)d_in[14];
    const float* bn_mem3   = (const float*)d_in[15];
    const float* W_pix3    = (const float*)d_in[16];
    const float* bn_pix3   = (const float*)d_in[17];
    const float* W_ffn1    = (const float*)d_in[18];
    const float* bn_ffn1   = (const float*)d_in[19];
    const float* W_ffn2    = (const float*)d_in[20];
    const float* bn_ffn2   = (const float*)d_in[21];

    char* ws = (char*)d_ws;
    size_t off = 0;
    auto alloc = [&](size_t bytes) -> void* {
        void* p = ws + off; off += (bytes + 255) & ~(size_t)255; return p;
    };
    unsigned short* pixB  = (unsigned short*)alloc((size_t)32768*128*2);
    unsigned short* Wt0   = (unsigned short*)alloc((size_t)256*128*2);   // mem1
    unsigned short* Wt1   = (unsigned short*)alloc((size_t)256*128*2);   // pix1
    unsigned short* Wt2   = (unsigned short*)alloc((size_t)512*256*2);   // mem_qkv
    unsigned short* Wt3   = (unsigned short*)alloc((size_t)512*256*2);   // pix_qkv
    unsigned short* Wt4   = (unsigned short*)alloc((size_t)128*256*2);   // mem3
    unsigned short* Wt5   = (unsigned short*)alloc((size_t)128*256*2);   // pix3
    unsigned short* Wt6   = (unsigned short*)alloc((size_t)2048*128*2);  // ffn1
    unsigned short* Wt7   = (unsigned short*)alloc((size_t)128*2048*2);  // ffn2
    unsigned short* mqkvB = (unsigned short*)alloc((size_t)1024*512*2);
    unsigned short* pixA  = (unsigned short*)alloc((size_t)32768*256*2);
    unsigned short* pqkvB = (unsigned short*)alloc((size_t)32768*512*2);
    float* part_acc = (float*)alloc((size_t)64*MSPLIT*128*32*4);
    float* part_ml  = (float*)alloc((size_t)64*MSPLIT*128*2*4);
    unsigned short* pretB = (unsigned short*)alloc((size_t)32768*256*2);

    float* out_pix = (float*)d_out;
    float* out_mem = (float*)d_out + (size_t)8*4096*128;

    PrepPtrs P;
    P.src_pix = pixel_input;
    P.dst_pix = pixB;
    P.W[0]=W_mem1; P.W[1]=W_pix1; P.W[2]=W_mem_qkv; P.W[3]=W_pix_qkv;
    P.W[4]=W_mem3; P.W[5]=W_pix3; P.W[6]=W_ffn1;    P.W[7]=W_ffn2;
    P.Wt[0]=Wt0; P.Wt[1]=Wt1; P.Wt[2]=Wt2; P.Wt[3]=Wt3;
    P.Wt[4]=Wt4; P.Wt[5]=Wt5; P.Wt[6]=Wt6; P.Wt[7]=Wt7;

    dim3 blk(256);
    prep_kernel<<<4992, blk, 0, stream>>>(P);

    // pix = relu(bn(pixel @ W_pix1))           [32768 x 256, K=128]
    gemm_bf16<<<dim3(2,256,1), blk, 0, stream>>>(pixB, Wt1, bn_pix1, nullptr,
        pixA, nullptr, 32768, 128, 256, 1);
    // pqkv = bn(pix @ W_pix_qkv)               [32768 x 512, K=256]
    gemm_bf16<<<dim3(4,256,1), blk, 0, stream>>>(pixA, Wt3, bn_pix_qkv, nullptr,
        pqkvB, nullptr, 32768, 256, 512, 0);
    // mem path front: cast + mem1 + mqkv
    mem_fused<<<64, blk, 0, stream>>>(memory_input, Wt0, bn_mem1, Wt2, bn_mem_qkv, mqkvB);

    // memory attention (flash, MSPLIT-way key split)
    mem_attn<<<64*MSPLIT, blk, 0, stream>>>(mqkvB, pqkvB, bn_mem_sim, part_acc, part_ml);

    // mem path back: combine + mem3 + ffn1 + ffn2 (+residuals)
    ffn_fused<<<64, blk, 0, stream>>>(part_acc, part_ml, bn_mem_ret,
        Wt4, bn_mem3, memory_input, Wt6, bn_ffn1, Wt7, bn_ffn2, out_mem);

    // pixel attention
    pix_attn<<<2048, blk, 0, stream>>>(pqkvB, mqkvB, bn_pix_sim, bn_pix_ret, pretB);
    // pix_out = relu(pixel + bn(pret @ W_pix3))    [32768 x 128, K=256]
    gemm_bf16<<<dim3(1,256,1), blk, 0, stream>>>(pretB, Wt5, bn_pix3, pixel_input,
        nullptr, out_pix, 32768, 256, 128, 1);
}

// Round 5
// 262.756 us; speedup vs baseline: 1.2585x; 1.0796x over previous
//
#include <hip/hip_runtime.h>

typedef __attribute__((ext_vector_type(8))) short short8;
typedef __attribute__((ext_vector_type(4))) float floatx4;

#define INVC 0.9995003746877732f
#define MSPLIT 8

__device__ __forceinline__ unsigned short f2bf(float f) {
    union { float f; unsigned int u; } c; c.f = f;
    unsigned int r = c.u + 0x7fffu + ((c.u >> 16) & 1u);
    return (unsigned short)(r >> 16);
}
__device__ __forceinline__ float bf2f(unsigned short u) {
    union { unsigned int u; float f; } c; c.u = ((unsigned int)u) << 16;
    return c.f;
}
__device__ __forceinline__ void gld_lds16(const unsigned short* g, unsigned short* l) {
    __builtin_amdgcn_global_load_lds(
        (const __attribute__((address_space(1))) unsigned int*)g,
        (__attribute__((address_space(3))) unsigned int*)l, 16, 0, 0);
}
// A/B-frag index: element (row in 16-row unit, k) -> offset; unit stride 512
__device__ __forceinline__ int fidx(int row, int k) {
    return (k >> 5) * 512 + (row + 16 * ((k >> 3) & 3)) * 8 + (k & 7);
}

// ---------------------------------------------------------------------------
// Prep: fp32->bf16 cast of pixel input + transpose-cast of 8 weight matrices
// ---------------------------------------------------------------------------
struct PrepPtrs {
    const float* src_pix;
    unsigned short* dst_pix;
    const float* W[8]; unsigned short* Wt[8];
};

__global__ __launch_bounds__(256) void prep_kernel(PrepPtrs P) {
    __shared__ float T[32][33];
    const int bid = blockIdx.x, t = threadIdx.x;
    if (bid < 4096) {
        int i = bid * 1024 + t * 4;
        float4 v = *(const float4*)(P.src_pix + i);
        unsigned long long pk = (unsigned long long)f2bf(v.x)
            | ((unsigned long long)f2bf(v.y) << 16)
            | ((unsigned long long)f2bf(v.z) << 32)
            | ((unsigned long long)f2bf(v.w) << 48);
        *(unsigned long long*)(P.dst_pix + i) = pk;
        return;
    }
    int rel = bid - 4096;
    const int KD[8]  = {128,128,256,256,256,256,128,2048};
    const int ND[8]  = {256,256,512,512,128,128,2048,128};
    const int CNT[8] = {32,32,128,128,32,32,256,256};
    int wi = 0;
    #pragma unroll
    for (int k = 0; k < 8; ++k) { if (rel >= CNT[k] && wi == k) { rel -= CNT[k]; wi = k + 1; } }
    const int K = KD[wi], N = ND[wi];
    const int ntn = N >> 5;
    const int tn = rel % ntn, tk = rel / ntn;
    const int n0 = tn * 32, k0 = tk * 32;
    const float* W = P.W[wi];
    unsigned short* Wt = P.Wt[wi];
    const int tx = t & 31, ty = t >> 5;
    #pragma unroll
    for (int i = 0; i < 4; ++i)
        T[ty + 8*i][tx] = W[(size_t)(k0 + ty + 8*i) * N + n0 + tx];
    __syncthreads();
    #pragma unroll
    for (int i = 0; i < 4; ++i)
        Wt[(size_t)(n0 + ty + 8*i) * K + k0 + tx] = f2bf(T[tx][ty + 8*i]);
}

// ---------------------------------------------------------------------------
// gemm device body: 128x128 tile, BK=32, 4 waves, fragment-ordered LDS
// ---------------------------------------------------------------------------
__device__ __forceinline__ void gemm_body(
    const unsigned short* __restrict__ A,
    const unsigned short* __restrict__ Bt,
    const float* __restrict__ bnp,
    const float* __restrict__ residF,
    unsigned short* __restrict__ outB,
    float* __restrict__ outF,
    int K, int Nc, int do_relu, int row0, int col0,
    unsigned short* As, unsigned short* Bs)
{
    const int t = threadIdx.x;
    const int lane = t & 63, w = t >> 6;
    const int l15 = lane & 15, quad = lane >> 4;
    const int wr = w >> 1, wc = w & 1;

    floatx4 acc[4][4];
    #pragma unroll
    for (int i = 0; i < 4; ++i)
        #pragma unroll
        for (int j = 0; j < 4; ++j) acc[i][j] = (floatx4){0.f, 0.f, 0.f, 0.f};

    const unsigned short* gA0 = A  + (size_t)(row0 + w*16     + l15) * K + quad*8;
    const unsigned short* gA1 = A  + (size_t)(row0 + (w+4)*16 + l15) * K + quad*8;
    const unsigned short* gB0 = Bt + (size_t)(col0 + w*16     + l15) * K + quad*8;
    const unsigned short* gB1 = Bt + (size_t)(col0 + (w+4)*16 + l15) * K + quad*8;
    unsigned short* lA0 = &As[w * 512];
    unsigned short* lA1 = &As[(w + 4) * 512];
    unsigned short* lB0 = &Bs[w * 512];
    unsigned short* lB1 = &Bs[(w + 4) * 512];

    for (int k0 = 0; k0 < K; k0 += 32) {
        __syncthreads();
        gld_lds16(gA0 + k0, lA0);
        gld_lds16(gA1 + k0, lA1);
        gld_lds16(gB0 + k0, lB0);
        gld_lds16(gB1 + k0, lB1);
        __syncthreads();
        short8 a[4], b[4];
        #pragma unroll
        for (int mt = 0; mt < 4; ++mt) a[mt] = *(const short8*)&As[(wr*4 + mt)*512 + lane*8];
        #pragma unroll
        for (int nt = 0; nt < 4; ++nt) b[nt] = *(const short8*)&Bs[(wc*4 + nt)*512 + lane*8];
        #pragma unroll
        for (int mt = 0; mt < 4; ++mt)
            #pragma unroll
            for (int nt = 0; nt < 4; ++nt)
                acc[mt][nt] = __builtin_amdgcn_mfma_f32_16x16x32_bf16(a[mt], b[nt], acc[mt][nt], 0, 0, 0);
    }

    #pragma unroll
    for (int mt = 0; mt < 4; ++mt) {
        const int rowb = row0 + wr*64 + mt*16 + quad*4;
        #pragma unroll
        for (int nt = 0; nt < 4; ++nt) {
            const int col = col0 + wc*64 + nt*16 + l15;
            floatx4 v = acc[mt][nt];
            const float g  = bnp[col] * INVC;
            const float be = bnp[Nc + col];
            #pragma unroll
            for (int r = 0; r < 4; ++r) {
                size_t off = (size_t)(rowb + r) * Nc + col;
                float v1 = v[r] * g + be;
                if (residF) v1 += residF[off];
                if (do_relu) v1 = fmaxf(v1, 0.f);
                if (outB) outB[off] = f2bf(v1);
                if (outF) outF[off] = v1;
            }
        }
    }
}

// standalone gemm (pqkv)
__global__ __launch_bounds__(256, 4) void gemm_bf16(
    const unsigned short* __restrict__ A, const unsigned short* __restrict__ Bt,
    const float* __restrict__ bnp, unsigned short* __restrict__ outB,
    int K, int Nc)
{
    __shared__ unsigned short As[8 * 512];
    __shared__ unsigned short Bs[8 * 512];
    gemm_body(A, Bt, bnp, nullptr, outB, nullptr, K, Nc, 0,
              blockIdx.y * 128, blockIdx.x * 128, As, Bs);
}

// ---------------------------------------------------------------------------
// L2: pix1 gemm (512 blocks) + mem_fused cast+mem1+mqkv (64 blocks)
// ---------------------------------------------------------------------------
__global__ __launch_bounds__(256) void k_pix1_memfused(
    const unsigned short* __restrict__ pixB, const unsigned short* __restrict__ Wt1,
    const float* __restrict__ bn_pix1, unsigned short* __restrict__ pixA,
    const float* __restrict__ memory_input,
    const unsigned short* __restrict__ Wt0, const float* __restrict__ bn1,
    const unsigned short* __restrict__ Wt2, const float* __restrict__ bnq,
    unsigned short* __restrict__ mqkv)
{
    __shared__ unsigned short As[8 * 512];
    __shared__ unsigned short Bs[8 * 512];
    const int bx = blockIdx.x;
    if (bx < 512) {
        gemm_body(pixB, Wt1, bn_pix1, nullptr, pixA, nullptr, 128, 256, 1,
                  (bx >> 1) * 128, (bx & 1) * 128, As, Bs);
        return;
    }
    // mem_fused
    unsigned short* A0 = As;       // 4*512
    unsigned short* A1 = Bs;       // 8*512
    const int t = threadIdx.x;
    const int lane = t & 63, w = t >> 6;
    const int l15 = lane & 15, quad = lane >> 4;
    const int g0 = (bx - 512) * 16;

    {   // cast 16x128 fp32 -> A-frag
        const int row = t >> 4;
        const int c0 = (t & 15) * 8;
        const float* src = memory_input + (size_t)(g0 + row) * 128 + c0;
        float4 v0 = *(const float4*)src;
        float4 v1 = *(const float4*)(src + 4);
        float vv[8] = {v0.x, v0.y, v0.z, v0.w, v1.x, v1.y, v1.z, v1.w};
        #pragma unroll
        for (int e = 0; e < 8; ++e)
            A0[fidx(row, c0 + e)] = f2bf(vv[e]);
    }
    __syncthreads();

    // mem1: M=16, N=256, K=128
    #pragma unroll
    for (int i = 0; i < 4; ++i) {
        const int n0 = (w*4 + i) * 16;
        floatx4 acc = {0.f,0.f,0.f,0.f};
        #pragma unroll
        for (int kc = 0; kc < 4; ++kc) {
            short8 a = *(const short8*)&A0[kc*512 + lane*8];
            short8 bfr = *(const short8*)&Wt0[(size_t)(n0 + l15)*128 + kc*32 + quad*8];
            acc = __builtin_amdgcn_mfma_f32_16x16x32_bf16(a, bfr, acc, 0, 0, 0);
        }
        const int col = n0 + l15;
        const float g = bn1[col] * INVC, be = bn1[256 + col];
        #pragma unroll
        for (int r = 0; r < 4; ++r) {
            const int row = quad*4 + r;
            float v = fmaxf(acc[r]*g + be, 0.f);
            A1[fidx(row, col)] = f2bf(v);
        }
    }
    __syncthreads();

    // mqkv: M=16, N=512, K=256
    #pragma unroll
    for (int i = 0; i < 8; ++i) {
        const int n0 = w*128 + i*16;
        floatx4 acc = {0.f,0.f,0.f,0.f};
        #pragma unroll
        for (int kc = 0; kc < 8; ++kc) {
            short8 a = *(const short8*)&A1[kc*512 + lane*8];
            short8 bfr = *(const short8*)&Wt2[(size_t)(n0 + l15)*256 + kc*32 + quad*8];
            acc = __builtin_amdgcn_mfma_f32_16x16x32_bf16(a, bfr, acc, 0, 0, 0);
        }
        const int col = n0 + l15;
        const float g = bnq[col] * INVC, be = bnq[512 + col];
        #pragma unroll
        for (int r = 0; r < 4; ++r) {
            const int row = quad*4 + r;
            mqkv[(size_t)(g0 + row)*512 + col] = f2bf(acc[r]*g + be);
        }
    }
}

// ---------------------------------------------------------------------------
// L4: pix_attn (2048 blocks) + mem_attn flash (512 blocks)
// ---------------------------------------------------------------------------
__global__ __launch_bounds__(256) void k_attn(
    const unsigned short* __restrict__ pqkv,
    const unsigned short* __restrict__ mqkv,
    const float* __restrict__ bn_psim, const float* __restrict__ bn_pret,
    unsigned short* __restrict__ pret,
    const float* __restrict__ bn_msim,
    float* __restrict__ part_acc, float* __restrict__ part_ml)
{
    __shared__ unsigned short Qs[128][40];
    __shared__ unsigned short Ks[128][40];
    __shared__ unsigned short VsT[32][136];
    __shared__ unsigned short Ps[128][136];
    const int t = threadIdx.x;
    const int lane = t & 63, w = t >> 6;
    const int l15 = lane & 15, quad = lane >> 4;
    floatx4 z4 = {0.f, 0.f, 0.f, 0.f};

    if (blockIdx.x < 2048) {
        const int bx = blockIdx.x;
        const int lt = bx & 31, h = (bx >> 5) & 7, b = bx >> 8;
        const int l0 = lt * 128;
        const float simg = bn_psim[h] * INVC, simb = bn_psim[8 + h];
        {
            const int r = t >> 1, half = t & 1;
            uint4 zz = make_uint4(0u, 0u, 0u, 0u);
            const unsigned short* qsrc = pqkv + ((size_t)(b*4096 + l0 + r) << 9) + h*16 + half*8;
            *(uint4*)&Qs[r][half*8] = *(const uint4*)qsrc;
            *(uint4*)&Qs[r][16 + half*8] = zz;
            const unsigned short* ksrc = mqkv + ((size_t)(b*128 + r) << 9) + 128 + h*16 + half*8;
            *(uint4*)&Ks[r][half*8] = *(const uint4*)ksrc;
            *(uint4*)&Ks[r][16 + half*8] = zz;
            const unsigned short* vsrc = mqkv + ((size_t)(b*128 + r) << 9) + 256 + h*32 + half*16;
            uint4 va = *(const uint4*)vsrc;
            uint4 vb = *(const uint4*)(vsrc + 8);
            const int d0 = half * 16;
            VsT[d0+0][r] = (unsigned short)(va.x & 0xffffu); VsT[d0+1][r] = (unsigned short)(va.x >> 16);
            VsT[d0+2][r] = (unsigned short)(va.y & 0xffffu); VsT[d0+3][r] = (unsigned short)(va.y >> 16);
            VsT[d0+4][r] = (unsigned short)(va.z & 0xffffu); VsT[d0+5][r] = (unsigned short)(va.z >> 16);
            VsT[d0+6][r] = (unsigned short)(va.w & 0xffffu); VsT[d0+7][r] = (unsigned short)(va.w >> 16);
            VsT[d0+8][r] = (unsigned short)(vb.x & 0xffffu); VsT[d0+9][r] = (unsigned short)(vb.x >> 16);
            VsT[d0+10][r] = (unsigned short)(vb.y & 0xffffu); VsT[d0+11][r] = (unsigned short)(vb.y >> 16);
            VsT[d0+12][r] = (unsigned short)(vb.z & 0xffffu); VsT[d0+13][r] = (unsigned short)(vb.z >> 16);
            VsT[d0+14][r] = (unsigned short)(vb.w & 0xffffu); VsT[d0+15][r] = (unsigned short)(vb.w >> 16);
        }
        __syncthreads();
        #pragma unroll
        for (int half = 0; half < 2; ++half) {
            short8 aq = *(const short8*)&Qs[w*32 + half*16 + l15][quad*8];
            #pragma unroll
            for (int nt = 0; nt < 8; ++nt) {
                short8 bk = *(const short8*)&Ks[nt*16 + l15][quad*8];
                floatx4 s = __builtin_amdgcn_mfma_f32_16x16x32_bf16(aq, bk, z4, 0, 0, 0);
                const int rowb = w*32 + half*16 + quad*4;
                #pragma unroll
                for (int r = 0; r < 4; ++r) {
                    float x = s[r] * simg + simb;
                    float p = 1.f / (1.f + __expf(-x));
                    Ps[rowb + r][nt*16 + l15] = f2bf(p);
                }
            }
        }
        __syncthreads();
        #pragma unroll
        for (int half = 0; half < 2; ++half) {
            const int mrow = w*32 + half*16;
            #pragma unroll
            for (int dvt = 0; dvt < 2; ++dvt) {
                floatx4 acc = {0.f, 0.f, 0.f, 0.f};
                #pragma unroll
                for (int ks = 0; ks < 4; ++ks) {
                    short8 ap = *(const short8*)&Ps[mrow + l15][ks*32 + quad*8];
                    short8 bv = *(const short8*)&VsT[dvt*16 + l15][ks*32 + quad*8];
                    acc = __builtin_amdgcn_mfma_f32_16x16x32_bf16(ap, bv, acc, 0, 0, 0);
                }
                const int dv = dvt*16 + l15;
                const float g  = bn_pret[h*32 + dv] * INVC;
                const float be = bn_pret[256 + h*32 + dv];
                #pragma unroll
                for (int r = 0; r < 4; ++r) {
                    const int row = l0 + mrow + quad*4 + r;
                    float v = fmaxf(acc[r] * g + be, 0.f);
                    pret[((size_t)(b*4096 + row) << 8) + h*32 + dv] = f2bf(v);
                }
            }
        }
        return;
    }

    // ---- mem_attn ----
    const int bxm = blockIdx.x - 2048;
    const int s = bxm & (MSPLIT-1), h = (bxm >> 3) & 7, b = bxm >> 6;
    const int bh = b*8 + h;
    const float simg = bn_msim[h] * INVC, simb = bn_msim[8 + h];
    const int c0  = (s == 0) ? 0 : (4*s + 1);
    const int cnt = (s == 0) ? 5 : 4;

    {
        const int r = t >> 1, half = t & 1;
        uint4 zz = make_uint4(0u, 0u, 0u, 0u);
        const unsigned short* qsrc = mqkv + ((size_t)(b*128 + r) << 9) + h*16 + half*8;
        *(uint4*)&Qs[r][half*8] = *(const uint4*)qsrc;
        *(uint4*)&Qs[r][16 + half*8] = zz;
    }

    float m_run[2][4], l_run[2][4];
    floatx4 accpv[2][2];
    #pragma unroll
    for (int i = 0; i < 2; ++i) {
        #pragma unroll
        for (int r = 0; r < 4; ++r) { m_run[i][r] = -1e30f; l_run[i][r] = 0.f; }
        accpv[i][0] = (floatx4){0.f,0.f,0.f,0.f};
        accpv[i][1] = (floatx4){0.f,0.f,0.f,0.f};
    }

    for (int ci = 0; ci < cnt; ++ci) {
        const int c = c0 + ci;
        __syncthreads();
        {
            const int r = t >> 1, half = t & 1;
            uint4 zz = make_uint4(0u, 0u, 0u, 0u);
            const unsigned short* base = (c < 32)
                ? (pqkv + ((size_t)(b*4096 + c*128 + r) << 9))
                : (mqkv + ((size_t)(b*128 + r) << 9));
            *(uint4*)&Ks[r][half*8] = *(const uint4*)(base + 128 + h*16 + half*8);
            *(uint4*)&Ks[r][16 + half*8] = zz;
            const unsigned short* vsrc = base + 256 + h*32 + half*16;
            uint4 va = *(const uint4*)vsrc;
            uint4 vb = *(const uint4*)(vsrc + 8);
            const int d0 = half * 16;
            VsT[d0+0][r] = (unsigned short)(va.x & 0xffffu); VsT[d0+1][r] = (unsigned short)(va.x >> 16);
            VsT[d0+2][r] = (unsigned short)(va.y & 0xffffu); VsT[d0+3][r] = (unsigned short)(va.y >> 16);
            VsT[d0+4][r] = (unsigned short)(va.z & 0xffffu); VsT[d0+5][r] = (unsigned short)(va.z >> 16);
            VsT[d0+6][r] = (unsigned short)(va.w & 0xffffu); VsT[d0+7][r] = (unsigned short)(va.w >> 16);
            VsT[d0+8][r] = (unsigned short)(vb.x & 0xffffu); VsT[d0+9][r] = (unsigned short)(vb.x >> 16);
            VsT[d0+10][r] = (unsigned short)(vb.y & 0xffffu); VsT[d0+11][r] = (unsigned short)(vb.y >> 16);
            VsT[d0+12][r] = (unsigned short)(vb.z & 0xffffu); VsT[d0+13][r] = (unsigned short)(vb.z >> 16);
            VsT[d0+14][r] = (unsigned short)(vb.w & 0xffffu); VsT[d0+15][r] = (unsigned short)(vb.w >> 16);
        }
        __syncthreads();

        #pragma unroll
        for (int half = 0; half < 2; ++half) {
            float sv[8][4];
            short8 aq = *(const short8*)&Qs[w*32 + half*16 + l15][quad*8];
            #pragma unroll
            for (int nt = 0; nt < 8; ++nt) {
                short8 bk = *(const short8*)&Ks[nt*16 + l15][quad*8];
                floatx4 sr4 = __builtin_amdgcn_mfma_f32_16x16x32_bf16(aq, bk, z4, 0, 0, 0);
                #pragma unroll
                for (int r = 0; r < 4; ++r) sv[nt][r] = sr4[r] * simg + simb;
            }
            const int rowb = w*32 + half*16 + quad*4;
            #pragma unroll
            for (int r = 0; r < 4; ++r) {
                float mx = sv[0][r];
                #pragma unroll
                for (int nt = 1; nt < 8; ++nt) mx = fmaxf(mx, sv[nt][r]);
                mx = fmaxf(mx, __shfl_xor(mx, 1));
                mx = fmaxf(mx, __shfl_xor(mx, 2));
                mx = fmaxf(mx, __shfl_xor(mx, 4));
                mx = fmaxf(mx, __shfl_xor(mx, 8));
                float newm  = fmaxf(m_run[half][r], mx);
                float alpha = __expf(m_run[half][r] - newm);
                m_run[half][r] = newm;
                float lsum = 0.f;
                #pragma unroll
                for (int nt = 0; nt < 8; ++nt) {
                    float p = __expf(sv[nt][r] - newm);
                    lsum += p;
                    Ps[rowb + r][nt*16 + l15] = f2bf(p);
                }
                lsum += __shfl_xor(lsum, 1);
                lsum += __shfl_xor(lsum, 2);
                lsum += __shfl_xor(lsum, 4);
                lsum += __shfl_xor(lsum, 8);
                l_run[half][r] = l_run[half][r] * alpha + lsum;
                accpv[half][0][r] *= alpha;
                accpv[half][1][r] *= alpha;
            }
            __syncthreads();
            const int mrow = w*32 + half*16;
            #pragma unroll
            for (int dvt = 0; dvt < 2; ++dvt) {
                floatx4 a = accpv[half][dvt];
                #pragma unroll
                for (int ks = 0; ks < 4; ++ks) {
                    short8 ap = *(const short8*)&Ps[mrow + l15][ks*32 + quad*8];
                    short8 bv = *(const short8*)&VsT[dvt*16 + l15][ks*32 + quad*8];
                    a = __builtin_amdgcn_mfma_f32_16x16x32_bf16(ap, bv, a, 0, 0, 0);
                }
                accpv[half][dvt] = a;
            }
        }
    }

    #pragma unroll
    for (int half = 0; half < 2; ++half) {
        const int rowb = w*32 + half*16 + quad*4;
        #pragma unroll
        for (int dvt = 0; dvt < 2; ++dvt) {
            const int dv = dvt*16 + l15;
            #pragma unroll
            for (int r = 0; r < 4; ++r)
                part_acc[((size_t)(bh*MSPLIT + s)*128 + rowb + r)*32 + dv] = accpv[half][dvt][r];
        }
        if (l15 == 0) {
            #pragma unroll
            for (int r = 0; r < 4; ++r) {
                size_t o = ((size_t)(bh*MSPLIT + s)*128 + rowb + r) * 2;
                part_ml[o]     = m_run[half][r];
                part_ml[o + 1] = l_run[half][r];
            }
        }
    }
}

// ---------------------------------------------------------------------------
// L5: pix3 gemm (256 blocks) + [flash-combine + mem3 -> moB] (64 blocks)
// ---------------------------------------------------------------------------
__global__ __launch_bounds__(256) void k_pix3_combmem3(
    const unsigned short* __restrict__ pretB, const unsigned short* __restrict__ Wt5,
    const float* __restrict__ bn_pix3, const float* __restrict__ pixel_input,
    float* __restrict__ out_pix,
    const float* __restrict__ part_acc, const float* __restrict__ part_ml,
    const float* __restrict__ bn_ret,
    const unsigned short* __restrict__ Wt4, const float* __restrict__ bn3,
    const float* __restrict__ memory_input,
    unsigned short* __restrict__ moB)
{
    __shared__ unsigned short As[8 * 512];
    __shared__ unsigned short Bs[8 * 512];
    const int bx = blockIdx.x;
    if (bx < 256) {
        gemm_body(pretB, Wt5, bn_pix3, pixel_input, nullptr, out_pix, 256, 128, 1,
                  bx * 128, 0, As, Bs);
        return;
    }
    unsigned short* mretA = As;    // 8*512
    const int t = threadIdx.x;
    const int lane = t & 63, w = t >> 6;
    const int l15 = lane & 15, quad = lane >> 4;
    const int g0 = (bx - 256) * 16;
    const int b = g0 >> 7;
    const int nbase = g0 & 127;

    {   // flash combine -> mretA (16 x 256)
        const int row = t >> 4;
        const int c0 = (t & 15) * 16;
        const int h = c0 >> 5;
        const int n = nbase + row;
        const int bh = b*8 + h;
        float ms[MSPLIT], ls[MSPLIT], m_g = -1e30f;
        #pragma unroll
        for (int s = 0; s < MSPLIT; ++s) {
            size_t o = ((size_t)(bh*MSPLIT + s)*128 + n)*2;
            ms[s] = part_ml[o]; ls[s] = part_ml[o+1];
            m_g = fmaxf(m_g, ms[s]);
        }
        float l_g = 0.f;
        float og[16];
        #pragma unroll
        for (int e = 0; e < 16; ++e) og[e] = 0.f;
        #pragma unroll
        for (int s = 0; s < MSPLIT; ++s) {
            float wgt = __expf(ms[s] - m_g);
            l_g += ls[s] * wgt;
            const float* pa = part_acc + ((size_t)(bh*MSPLIT + s)*128 + n)*32 + (c0 & 31);
            #pragma unroll
            for (int e = 0; e < 16; e += 4) {
                float4 v = *(const float4*)(pa + e);
                og[e]   += v.x*wgt; og[e+1] += v.y*wgt;
                og[e+2] += v.z*wgt; og[e+3] += v.w*wgt;
            }
        }
        float invl = 1.f / l_g;
        #pragma unroll
        for (int e = 0; e < 16; ++e) {
            int col = c0 + e;
            int dv = col & 31;
            float v = og[e]*invl*(bn_ret[h*32+dv]*INVC) + bn_ret[256 + h*32 + dv];
            mretA[fidx(row, col)] = f2bf(fmaxf(v, 0.f));
        }
    }
    __syncthreads();

    // mem3: M=16,N=128,K=256 -> moB (bf16, relu(resid))
    #pragma unroll
    for (int i = 0; i < 2; ++i) {
        const int n0 = (w*2 + i) * 16;
        floatx4 acc = {0.f,0.f,0.f,0.f};
        #pragma unroll
        for (int kc = 0; kc < 8; ++kc) {
            short8 a = *(const short8*)&mretA[kc*512 + lane*8];
            short8 bfr = *(const short8*)&Wt4[(size_t)(n0 + l15)*256 + kc*32 + quad*8];
            acc = __builtin_amdgcn_mfma_f32_16x16x32_bf16(a, bfr, acc, 0, 0, 0);
        }
        const int col = n0 + l15;
        const float g = bn3[col]*INVC, be = bn3[128 + col];
        #pragma unroll
        for (int r = 0; r < 4; ++r) {
            const int row = quad*4 + r;
            float v = acc[r]*g + be + memory_input[(size_t)(g0 + row)*128 + col];
            moB[(size_t)(g0 + row)*128 + col] = f2bf(fmaxf(v, 0.f));
        }
    }
}

// ---------------------------------------------------------------------------
// L6: ffn1+ffn2, 64 blocks x 1024 threads (16 waves)
// ---------------------------------------------------------------------------
__global__ __launch_bounds__(1024) void k_ffn(
    const unsigned short* __restrict__ moB,
    const unsigned short* __restrict__ Wt6, const float* __restrict__ bnf1,
    const unsigned short* __restrict__ Wt7, const float* __restrict__ bnf2,
    float* __restrict__ out_mem)
{
    __shared__ unsigned short moA[4*512];
    __shared__ unsigned short fA[64*512];
    __shared__ floatx4 red[2][8][64];
    const int t = threadIdx.x;
    const int lane = t & 63, w = t >> 6;      // 16 waves
    const int l15 = lane & 15, quad = lane >> 4;
    const int g0 = blockIdx.x * 16;

    if (t < 256) {  // load moB 16x128 -> A-frag
        const int row = t >> 4;
        const int c0 = (t & 15) * 8;
        uint4 v = *(const uint4*)(moB + (size_t)(g0 + row)*128 + c0);
        unsigned short e0 = (unsigned short)(v.x & 0xffffu), e1 = (unsigned short)(v.x >> 16);
        unsigned short e2 = (unsigned short)(v.y & 0xffffu), e3 = (unsigned short)(v.y >> 16);
        unsigned short e4 = (unsigned short)(v.z & 0xffffu), e5 = (unsigned short)(v.z >> 16);
        unsigned short e6 = (unsigned short)(v.w & 0xffffu), e7 = (unsigned short)(v.w >> 16);
        moA[fidx(row, c0+0)] = e0; moA[fidx(row, c0+1)] = e1;
        moA[fidx(row, c0+2)] = e2; moA[fidx(row, c0+3)] = e3;
        moA[fidx(row, c0+4)] = e4; moA[fidx(row, c0+5)] = e5;
        moA[fidx(row, c0+6)] = e6; moA[fidx(row, c0+7)] = e7;
    }
    __syncthreads();

    // ffn1: M=16, N=2048, K=128; wave w covers n in [w*128, (w+1)*128)
    #pragma unroll
    for (int i = 0; i < 8; ++i) {
        const int n0 = (w*8 + i) * 16;
        floatx4 acc = {0.f,0.f,0.f,0.f};
        #pragma unroll
        for (int kc = 0; kc < 4; ++kc) {
            short8 a = *(const short8*)&moA[kc*512 + lane*8];
            short8 bfr = *(const short8*)&Wt6[(size_t)(n0 + l15)*128 + kc*32 + quad*8];
            acc = __builtin_amdgcn_mfma_f32_16x16x32_bf16(a, bfr, acc, 0, 0, 0);
        }
        const int col = n0 + l15;
        const float g = bnf1[col]*INVC, be = bnf1[2048 + col];
        #pragma unroll
        for (int r = 0; r < 4; ++r)
            fA[fidx(quad*4 + r, col)] = f2bf(fmaxf(acc[r]*g + be, 0.f));
    }
    __syncthreads();

    // ffn2: M=16, N=128, K=2048; wave w: ntile = w&7, k-half = w>>3
    {
        const int ntile = w & 7, khalf = w >> 3;
        const int n0 = ntile * 16;
        floatx4 acc = {0.f,0.f,0.f,0.f};
        #pragma unroll 8
        for (int kc = 0; kc < 32; ++kc) {
            const int kcu = khalf*32 + kc;
            short8 a = *(const short8*)&fA[kcu*512 + lane*8];
            short8 bfr = *(const short8*)&Wt7[(size_t)(n0 + l15)*2048 + kcu*32 + quad*8];
            acc = __builtin_amdgcn_mfma_f32_16x16x32_bf16(a, bfr, acc, 0, 0, 0);
        }
        red[khalf][ntile][lane] = acc;
    }
    __syncthreads();
    if (w < 8) {
        const int n0 = w * 16;
        floatx4 s0 = red[0][w][lane];
        floatx4 s1 = red[1][w][lane];
        const int col = n0 + l15;
        const float g = bnf2[col]*INVC, be = bnf2[128 + col];
        #pragma unroll
        for (int r = 0; r < 4; ++r) {
            const int row = quad*4 + r;
            float resid = bf2f(moA[fidx(row, col)]);
            float v = fmaxf((s0[r] + s1[r])*g + be + resid, 0.f);
            out_mem[(size_t)(g0 + row)*128 + col] = v;
        }
    }
}

// ---------------------------------------------------------------------------
extern "C" void kernel_launch(void* const* d_in, const int* in_sizes, int n_in,
                              void* d_out, int out_size, void* d_ws, size_t ws_size,
                              hipStream_t stream) {
    const float* pixel_input  = (const float*)d_in[0];
    const float* memory_input = (const float*)d_in[1];
    const float* W_mem1    = (const float*)d_in[2];
    const float* bn_mem1   = (const float*)d_in[3];
    const float* W_pix1    = (const float*)d_in[4];
    const float* bn_pix1   = (const float*)d_in[5];
    const float* W_mem_qkv = (const float*)d_in[6];
    const float* bn_mem_qkv= (const float*)d_in[7];
    const float* W_pix_qkv = (const float*)d_in[8];
    const float* bn_pix_qkv= (const float*)d_in[9];
    const float* bn_mem_sim= (const float*)d_in[10];
    const float* bn_mem_ret= (const float*)d_in[11];
    const float* bn_pix_sim= (const float*)d_in[12];
    const float* bn_pix_ret= (const float*)d_in[13];
    const float* W_mem3    = (const float*)d_in[14];
    const float* bn_mem3   = (const float*)d_in[15];
    const float* W_pix3    = (const float*)d_in[16];
    const float* bn_pix3   = (const float*)d_in[17];
    const float* W_ffn1    = (const float*)d_in[18];
    const float* bn_ffn1   = (const float*)d_in[19];
    const float* W_ffn2    = (const float*)d_in[20];
    const float* bn_ffn2   = (const float*)d_in[21];

    char* ws = (char*)d_ws;
    size_t off = 0;
    auto alloc = [&](size_t bytes) -> void* {
        void* p = ws + off; off += (bytes + 255) & ~(size_t)255; return p;
    };
    unsigned short* pixB  = (unsigned short*)alloc((size_t)32768*128*2);
    unsigned short* Wt0   = (unsigned short*)alloc((size_t)256*128*2);
    unsigned short* Wt1   = (unsigned short*)alloc((size_t)256*128*2);
    unsigned short* Wt2   = (unsigned short*)alloc((size_t)512*256*2);
    unsigned short* Wt3   = (unsigned short*)alloc((size_t)512*256*2);
    unsigned short* Wt4   = (unsigned short*)alloc((size_t)128*256*2);
    unsigned short* Wt5   = (unsigned short*)alloc((size_t)128*256*2);
    unsigned short* Wt6   = (unsigned short*)alloc((size_t)2048*128*2);
    unsigned short* Wt7   = (unsigned short*)alloc((size_t)128*2048*2);
    unsigned short* mqkvB = (unsigned short*)alloc((size_t)1024*512*2);
    unsigned short* pixA  = (unsigned short*)alloc((size_t)32768*256*2);
    unsigned short* pqkvB = (unsigned short*)alloc((size_t)32768*512*2);
    float* part_acc = (float*)alloc((size_t)64*MSPLIT*128*32*4);
    float* part_ml  = (float*)alloc((size_t)64*MSPLIT*128*2*4);
    unsigned short* pretB = (unsigned short*)alloc((size_t)32768*256*2);
    unsigned short* moB   = (unsigned short*)alloc((size_t)1024*128*2);

    float* out_pix = (float*)d_out;
    float* out_mem = (float*)d_out + (size_t)8*4096*128;

    PrepPtrs P;
    P.src_pix = pixel_input;
    P.dst_pix = pixB;
    P.W[0]=W_mem1; P.W[1]=W_pix1; P.W[2]=W_mem_qkv; P.W[3]=W_pix_qkv;
    P.W[4]=W_mem3; P.W[5]=W_pix3; P.W[6]=W_ffn1;    P.W[7]=W_ffn2;
    P.Wt[0]=Wt0; P.Wt[1]=Wt1; P.Wt[2]=Wt2; P.Wt[3]=Wt3;
    P.Wt[4]=Wt4; P.Wt[5]=Wt5; P.Wt[6]=Wt6; P.Wt[7]=Wt7;

    dim3 blk(256);
    // L1: casts + weight transposes
    prep_kernel<<<4992, blk, 0, stream>>>(P);
    // L2: pix1 gemm + mem front (cast+mem1+mqkv)
    k_pix1_memfused<<<576, blk, 0, stream>>>(pixB, Wt1, bn_pix1, pixA,
        memory_input, Wt0, bn_mem1, Wt2, bn_mem_qkv, mqkvB);
    // L3: pqkv gemm [32768 x 512, K=256]
    gemm_bf16<<<dim3(4,256,1), blk, 0, stream>>>(pixA, Wt3, bn_pix_qkv, pqkvB, 256, 512);
    // L4: pixel attention + memory flash attention
    k_attn<<<2048 + 64*MSPLIT, blk, 0, stream>>>(pqkvB, mqkvB,
        bn_pix_sim, bn_pix_ret, pretB, bn_mem_sim, part_acc, part_ml);
    // L5: pix3 gemm (+resid,relu -> out_pix) + combine+mem3 -> moB
    k_pix3_combmem3<<<320, blk, 0, stream>>>(pretB, Wt5, bn_pix3, pixel_input, out_pix,
        part_acc, part_ml, bn_mem_ret, Wt4, bn_mem3, memory_input, moB);
    // L6: ffn1+ffn2 -> out_mem
    k_ffn<<<64, dim3(1024), 0, stream>>>(moB, Wt6, bn_ffn1, Wt7, bn_ffn2, out_mem);
}